// Round 5
// baseline (352.702 us; speedup 1.0000x reference)
//
#include <hip/hip_runtime.h>
#include <hip/hip_bf16.h>

// Problem constants (fixed by the reference file)
#define LEAFN 1024
#define NN    2048            // nodes per batch incl. global node 0
#define BATCH 8
#define DD    128
#define ROWS  (BATCH*NN)      // 16384
#define AHS   256             // ah row stride: [agg(128) | h(128)] bf16
#define NB    256             // megakernel grid size (blocks)

// ln(10000)/32
#define LOG1E4_OVER_32 0.28782313662425575f

typedef __bf16 bf16x8 __attribute__((ext_vector_type(8)));
typedef float  floatx4 __attribute__((ext_vector_type(4)));

__device__ __forceinline__ float bf2f(unsigned short u) {
  return __uint_as_float(((unsigned)u) << 16);
}
__device__ __forceinline__ unsigned short f2bf(float f) {
  unsigned u = __float_as_uint(f);
  u += 0x7FFFu + ((u >> 16) & 1u);          // round-to-nearest-even
  return (unsigned short)(u >> 16);
}
__device__ __forceinline__ float gelu(float v) {
  return 0.5f * v * (1.0f + erff(v * 0.70710678118f));
}
__device__ __forceinline__ void cvt8(uint4 u, float* f) {
  f[0] = __uint_as_float(u.x << 16); f[1] = __uint_as_float(u.x & 0xffff0000u);
  f[2] = __uint_as_float(u.y << 16); f[3] = __uint_as_float(u.y & 0xffff0000u);
  f[4] = __uint_as_float(u.z << 16); f[5] = __uint_as_float(u.z & 0xffff0000u);
  f[6] = __uint_as_float(u.w << 16); f[7] = __uint_as_float(u.w & 0xffff0000u);
}

__device__ __forceinline__ float enc_val(int node, int d) {
  float hp, vp;
  if (node == 0) { hp = -0.5f; vp = -1.0f; }
  else {
    int v = 31 - __clz(node);
    hp = (float)(node - (1 << v));
    vp = (float)v;
  }
  float pos = (d < 64) ? hp : vp;
  int i = ((d < 64) ? d : (d - 64)) >> 1;
  float inv = expf(-(float)i * LOG1E4_OVER_32);
  float ang = pos * inv;
  return (d & 1) ? cosf(ang) : sinf(ang);
}

// ---------------------------------------------------------------------------
// Software grid barrier. One counter per barrier index (no generation reuse;
// counters zeroed by hipMemsetAsync before each kernel run). __threadfence()
// at agent scope emits the gfx94x+ L2 writeback/invalidate needed for
// cross-XCD visibility.
__device__ __forceinline__ void gbar(int* bar, int idx) {
  __syncthreads();
  if (threadIdx.x == 0) {
    __threadfence();                           // release
    __hip_atomic_fetch_add(&bar[idx * 32], 1, __ATOMIC_RELAXED,
                           __HIP_MEMORY_SCOPE_AGENT);
    while (__hip_atomic_load(&bar[idx * 32], __ATOMIC_RELAXED,
                             __HIP_MEMORY_SCOPE_AGENT) < NB)
      __builtin_amdgcn_s_sleep(2);
    __threadfence();                           // acquire
  }
  __syncthreads();
}

// ---------------------------------------------------------------------------
// Phase: tree build + layer-0 LN/GELU for depth>=4 nodes. blk in [0,128).
__device__ __forceinline__ void ph_tree(char* smemc, int blk,
                                        const float* __restrict__ elements,
                                        float* __restrict__ x,
                                        float* __restrict__ lvl4,
                                        unsigned short* __restrict__ ah,
                                        const float* __restrict__ gamma,
                                        const float* __restrict__ beta) {
  float* sm = (float*)smemc;                  // 127*128 floats = 63.5 KB
  int tid = threadIdx.x;
  int b = blk >> 4, s = blk & 15;
  const float4* src = (const float4*)(elements + (size_t)(b * LEAFN + s * 64) * DD);
  for (int i = tid; i < 2048; i += 256) {
    int f = i * 4;
    int j = f >> 7, d = f & 127;
    *(float4*)&sm[(63 + j) * DD + d] = src[i];
  }
  __syncthreads();
  for (int lv = 5; lv >= 0; --lv) {
    int nodes = 1 << lv;
    for (int idx = tid; idx < nodes * DD; idx += 256) {
      int k = nodes + (idx >> 7);
      int d = idx & 127;
      sm[(k - 1) * DD + d] = 0.5f * (sm[(2 * k - 1) * DD + d] + sm[(2 * k) * DD + d]);
    }
    __syncthreads();
  }
  if (tid < DD) lvl4[(b * 16 + s) * DD + tid] = sm[tid];
  __syncthreads();
  for (int idx = tid; idx < 127 * DD; idx += 256) {
    int k = (idx >> 7) + 1;
    int d = idx & 127;
    int lv = 31 - __clz(k);
    int g = ((16 + s) << lv) | (k - (1 << lv));
    float xv = sm[idx] + enc_val(g, d);
    x[((size_t)(b * NN + g)) * DD + d] = xv;
    sm[idx] = xv;
  }
  __syncthreads();
  int sub = tid & 7, dp = sub * 16;
  float gm[16], bt[16];
#pragma unroll
  for (int j = 0; j < 16; ++j) { gm[j] = gamma[dp + j]; bt[j] = beta[dp + j]; }
  for (int rr = tid >> 3; rr < 127; rr += 32) {
    float v[16], s1 = 0.f, s2 = 0.f;
#pragma unroll
    for (int j = 0; j < 16; ++j) { v[j] = sm[rr * DD + dp + j]; s1 += v[j]; s2 += v[j] * v[j]; }
    s1 += __shfl_xor(s1, 1); s2 += __shfl_xor(s2, 1);
    s1 += __shfl_xor(s1, 2); s2 += __shfl_xor(s2, 2);
    s1 += __shfl_xor(s1, 4); s2 += __shfl_xor(s2, 4);
    float mu = s1 * (1.0f / 128.0f);
    float var = s2 * (1.0f / 128.0f) - mu * mu;
    float rinv = rsqrtf(var + 1e-5f);
    int k = rr + 1, lv = 31 - __clz(k);
    int g = ((16 + s) << lv) | (k - (1 << lv));
    unsigned short o[16];
#pragma unroll
    for (int j = 0; j < 16; ++j)
      o[j] = f2bf(gelu((v[j] - mu) * rinv * gm[j] + bt[j]));
    unsigned short* dst = &ah[(size_t)(b * NN + g) * AHS + 128 + dp];
#pragma unroll
    for (int j = 0; j < 4; ++j) *(ushort4*)&dst[j * 4] = *(ushort4*)&o[j * 4];
  }
}

// ---------------------------------------------------------------------------
// Phase: top nodes 0..15 of batch b: finish tree, write x and layer-0 h.
__device__ __forceinline__ void ph_top(char* smemc, int b,
                                       const float* __restrict__ lvl4,
                                       float* __restrict__ x,
                                       unsigned short* __restrict__ ah,
                                       const float* __restrict__ gamma,
                                       const float* __restrict__ beta) {
  float (*xs)[DD] = (float(*)[DD])smemc;      // 16*128 floats = 8 KB
  int tid = threadIdx.x;
  if (tid < 128) {
    int d = tid;
    float v[16];
    for (int j = 0; j < 16; ++j) v[j] = lvl4[(b * 16 + j) * DD + d];
    for (int j = 0; j < 8; ++j) v[j] = 0.5f * (v[2 * j] + v[2 * j + 1]);
    for (int j = 0; j < 8; ++j) xs[8 + j][d] = v[j] + enc_val(8 + j, d);
    for (int j = 0; j < 4; ++j) v[j] = 0.5f * (v[2 * j] + v[2 * j + 1]);
    for (int j = 0; j < 4; ++j) xs[4 + j][d] = v[j] + enc_val(4 + j, d);
    for (int j = 0; j < 2; ++j) v[j] = 0.5f * (v[2 * j] + v[2 * j + 1]);
    for (int j = 0; j < 2; ++j) xs[2 + j][d] = v[j] + enc_val(2 + j, d);
    v[0] = 0.5f * (v[0] + v[1]);
    xs[1][d] = v[0] + enc_val(1, d);
    xs[0][d] = -1.0f + enc_val(0, d);
    for (int j = 0; j < 16; ++j) x[((size_t)(b * NN + j)) * DD + d] = xs[j][d];
  }
  __syncthreads();
  if (tid < 128) {
    int rr = tid >> 3, sub = tid & 7, dp = sub * 16;
    float w[16], s1 = 0.f, s2 = 0.f;
#pragma unroll
    for (int j = 0; j < 16; ++j) { w[j] = xs[rr][dp + j]; s1 += w[j]; s2 += w[j] * w[j]; }
    s1 += __shfl_xor(s1, 1); s2 += __shfl_xor(s2, 1);
    s1 += __shfl_xor(s1, 2); s2 += __shfl_xor(s2, 2);
    s1 += __shfl_xor(s1, 4); s2 += __shfl_xor(s2, 4);
    float mu = s1 * (1.0f / 128.0f);
    float var = s2 * (1.0f / 128.0f) - mu * mu;
    float rinv = rsqrtf(var + 1e-5f);
    unsigned short o[16];
#pragma unroll
    for (int j = 0; j < 16; ++j)
      o[j] = f2bf(gelu((w[j] - mu) * rinv * gamma[dp + j] + beta[dp + j]));
    unsigned short* dst = &ah[(size_t)(b * NN + rr) * AHS + 128 + dp];
#pragma unroll
    for (int j = 0; j < 4; ++j) *(ushort4*)&dst[j * 4] = *(ushort4*)&o[j * 4];
  }
}

// ---------------------------------------------------------------------------
// Phase: subtree sums for internal nodes depth 4..9, sb in [0,128).
__device__ __forceinline__ void ph_aggsub(char* smemc, int sb,
                                          unsigned short* ah,
                                          const int* __restrict__ s0a,
                                          const int* __restrict__ s1a,
                                          float* __restrict__ sroot) {
  floatx4 (*S)[32] = (floatx4(*)[32])smemc;   // 64*32*16 = 32 KB
  int tid = threadIdx.x;
  int b = sb >> 4, s = sb & 15;

  for (int idx = tid; idx < 32 * 32; idx += 256) {
    int k = 32 + (idx >> 5), q = idx & 31;
    int c = (16 + s) * 64 + (2 * k - 64);
    size_t a0 = (size_t)(b * NN + c) * AHS + 128 + q * 4;
    ushort4 u0 = *(const ushort4*)&ah[a0];
    ushort4 u1 = *(const ushort4*)&ah[a0 + AHS];
    floatx4 v;
    v[0] = bf2f(u0.x) + bf2f(u1.x);
    v[1] = bf2f(u0.y) + bf2f(u1.y);
    v[2] = bf2f(u0.z) + bf2f(u1.z);
    v[3] = bf2f(u0.w) + bf2f(u1.w);
    S[k][q] = v;
    int g = (16 + s) * 32 + (k - 32);
    int r = b * NN + g;
    float inv = 1.0f / (float)max(s1a[r] - s0a[r], 1);
    ushort4 o;
    o.x = f2bf(v[0] * inv); o.y = f2bf(v[1] * inv);
    o.z = f2bf(v[2] * inv); o.w = f2bf(v[3] * inv);
    *(ushort4*)&ah[(size_t)r * AHS + q * 4] = o;
  }
  __syncthreads();
  for (int lv = 4; lv >= 0; --lv) {
    int nk = 1 << lv;
    for (int idx = tid; idx < nk * 32; idx += 256) {
      int k = nk + (idx >> 5), q = idx & 31;
      int c = ((16 + s) << (lv + 1)) | (2 * k - 2 * nk);
      size_t a0 = (size_t)(b * NN + c) * AHS + 128 + q * 4;
      ushort4 u0 = *(const ushort4*)&ah[a0];
      ushort4 u1 = *(const ushort4*)&ah[a0 + AHS];
      floatx4 sc0 = S[2 * k][q], sc1 = S[2 * k + 1][q];
      floatx4 v;
      v[0] = bf2f(u0.x) + bf2f(u1.x) + sc0[0] + sc1[0];
      v[1] = bf2f(u0.y) + bf2f(u1.y) + sc0[1] + sc1[1];
      v[2] = bf2f(u0.z) + bf2f(u1.z) + sc0[2] + sc1[2];
      v[3] = bf2f(u0.w) + bf2f(u1.w) + sc0[3] + sc1[3];
      S[k][q] = v;
      int g = ((16 + s) << lv) | (k - nk);
      int r = b * NN + g;
      float inv = 1.0f / (float)max(s1a[r] - s0a[r], 1);
      ushort4 o;
      o.x = f2bf(v[0] * inv); o.y = f2bf(v[1] * inv);
      o.z = f2bf(v[2] * inv); o.w = f2bf(v[3] * inv);
      *(ushort4*)&ah[(size_t)r * AHS + q * 4] = o;
    }
    __syncthreads();
  }
  for (int q = tid; q < 32; q += 256)
    ((floatx4*)sroot)[(size_t)(b * 16 + s) * 32 + q] = S[1][q];
}

// ---------------------------------------------------------------------------
// Phase: leaf-row gather with per-level LDS window cache. bid in [0,256).
#define SLACK 10
#define CACHE_ROWS 220
#define CSTRIDE 136
__device__ __forceinline__ void ph_leafagg(char* smemc, int bid,
                                           const int* __restrict__ src,
                                           const int* __restrict__ s0a,
                                           const int* __restrict__ s1a,
                                           unsigned short* ah) {
  unsigned short* cache = (unsigned short*)smemc;  // 220*136*2 = 58.5 KB
  int tid = threadIdx.x;
  int b = bid >> 5, jb = bid & 31;
  int li0 = jb * 32;
  int g0 = 1024 + li0, g1 = g0 + 31;

  int lo[11], wd[11], off[11];
  int acc_off = 0;
  for (int cd = 10; cd >= 1; --cd) {
    int a0 = g0 >> (10 - cd), a1 = g1 >> (10 - cd);
    int l = a0 - SLACK, hgh = a1 + SLACK;
    int lvlo = 1 << cd, lvhi = (2 << cd) - 1;
    l = l < lvlo ? lvlo : l;
    hgh = hgh > lvhi ? lvhi : hgh;
    int w = hgh - l + 1;
    if (acc_off + w > CACHE_ROWS) w = CACHE_ROWS - acc_off;
    if (w < 0) w = 0;
    lo[cd] = l; wd[cd] = w; off[cd] = acc_off; acc_off += w;
  }
  for (int cd = 10; cd >= 1; --cd) {
    int w = wd[cd];
    for (int t = tid; t < w * 16; t += 256) {
      int row = t >> 4, seg = t & 15;
      *(uint4*)&cache[(off[cd] + row) * CSTRIDE + seg * 8] =
          *(const uint4*)&ah[(size_t)(b * NN + lo[cd] + row) * AHS + 128 + seg * 8];
    }
  }
  __syncthreads();

  int leaf = li0 + (tid >> 3);
  int dp = (tid & 7) * 16;
  int r = b * NN + 1024 + leaf;
  int e0 = s0a[r], e1 = s1a[r];
  float acc[16];
#pragma unroll
  for (int j = 0; j < 16; ++j) acc[j] = 0.f;
  for (int e = e0; e < e1; ++e) {
    int g = src[e] - b * NN;
    int lv = 31 - __clz(g);
    int idx = g - lo[lv];
    float f[16];
    if ((unsigned)idx < (unsigned)wd[lv]) {
      const unsigned short* p = &cache[(off[lv] + idx) * CSTRIDE + dp];
      cvt8(*(const uint4*)p, f);
      cvt8(*(const uint4*)(p + 8), f + 8);
    } else {
      const unsigned short* p = &ah[(size_t)(b * NN + g) * AHS + 128 + dp];
      cvt8(*(const uint4*)p, f);
      cvt8(*(const uint4*)(p + 8), f + 8);
    }
#pragma unroll
    for (int j = 0; j < 16; ++j) acc[j] += f[j];
  }
  float inv = 1.0f / (float)max(e1 - e0, 1);
  unsigned short o[16];
#pragma unroll
  for (int j = 0; j < 16; ++j) o[j] = f2bf(acc[j] * inv);
  unsigned short* dst = &ah[(size_t)r * AHS + dp];
#pragma unroll
  for (int j = 0; j < 4; ++j) *(ushort4*)&dst[j * 4] = *(ushort4*)&o[j * 4];
}

// ---------------------------------------------------------------------------
// Phase: finish agg for nodes 0..15 of batch b (threads 0..127 only).
__device__ __forceinline__ void ph_topfin(int b,
                                          const float* __restrict__ sroot,
                                          const int* __restrict__ s0a,
                                          const int* __restrict__ s1a,
                                          unsigned short* ah) {
  int d = threadIdx.x;
  float S16[16], h16[16], Sv[16];
#pragma unroll
  for (int j = 0; j < 16; ++j) S16[j] = sroot[(size_t)(b * 16 + j) * DD + d];
#pragma unroll
  for (int j = 0; j < 16; ++j)
    h16[j] = bf2f(ah[(size_t)(b * NN + 16 + j) * AHS + 128 + d]);
#pragma unroll
  for (int k = 8; k < 16; ++k)
    Sv[k] = h16[2 * k - 16] + h16[2 * k - 15] + S16[2 * k - 16] + S16[2 * k - 15];
#pragma unroll
  for (int k = 7; k >= 1; --k)
    Sv[k] = bf2f(ah[(size_t)(b * NN + 2 * k) * AHS + 128 + d]) +
            bf2f(ah[(size_t)(b * NN + 2 * k + 1) * AHS + 128 + d]) +
            Sv[2 * k] + Sv[2 * k + 1];
#pragma unroll
  for (int k = 1; k < 16; ++k) {
    int r = b * NN + k;
    float inv = 1.0f / (float)max(s1a[r] - s0a[r], 1);
    ah[(size_t)r * AHS + d] = f2bf(Sv[k] * inv);
  }
  ah[(size_t)(b * NN) * AHS + d] = f2bf(0.0f);
}

// ---------------------------------------------------------------------------
// Phase: x += [agg|h] @ [Wn;Wr] + bias (bf16 MFMA), 64 rows/block, optional
// fused next-layer LN+GELU writing h'.
__device__ __forceinline__ void ph_gemm(int bid,
                                        const unsigned short* __restrict__ ah_c,
                                        const unsigned short* __restrict__ wfl,
                                        const float* __restrict__ bn,
                                        float* __restrict__ x,
                                        const float* __restrict__ gamma,
                                        const float* __restrict__ beta,
                                        unsigned short* ah_w, int write_h) {
  int wave = threadIdx.x >> 6, lane = threadIdx.x & 63;
  int r0 = bid * 64 + wave * 16;
  int m = lane & 15, q = lane >> 4;
  const bf16x8* A0 = (const bf16x8*)(ah_c + (size_t)(r0 + m) * AHS + q * 8);
  const bf16x8* B  = (const bf16x8*)wfl + lane;
  floatx4 acc[8];
#pragma unroll
  for (int ct = 0; ct < 8; ++ct) acc[ct] = (floatx4){0.f, 0.f, 0.f, 0.f};

#pragma unroll
  for (int kc = 0; kc < 8; ++kc) {
    bf16x8 a0 = A0[kc * 4];
#pragma unroll
    for (int ct = 0; ct < 8; ++ct) {
      bf16x8 bb = B[(kc * 8 + ct) * 64];
      acc[ct] = __builtin_amdgcn_mfma_f32_16x16x32_bf16(a0, bb, acc[ct], 0, 0, 0);
    }
  }
  float s1[4] = {0.f, 0.f, 0.f, 0.f}, s2[4] = {0.f, 0.f, 0.f, 0.f};
#pragma unroll
  for (int ct = 0; ct < 8; ++ct) {
    int col = ct * 16 + m;
    float bias = bn[col];
#pragma unroll
    for (int r = 0; r < 4; ++r) {
      int row = r0 + q * 4 + r;
      float v = x[(size_t)row * DD + col] + acc[ct][r] + bias;
      x[(size_t)row * DD + col] = v;
      acc[ct][r] = v;
      s1[r] += v; s2[r] += v * v;
    }
  }
  if (write_h) {
#pragma unroll
    for (int r = 0; r < 4; ++r) {
      float a = s1[r], bq = s2[r];
      a += __shfl_xor(a, 1); bq += __shfl_xor(bq, 1);
      a += __shfl_xor(a, 2); bq += __shfl_xor(bq, 2);
      a += __shfl_xor(a, 4); bq += __shfl_xor(bq, 4);
      a += __shfl_xor(a, 8); bq += __shfl_xor(bq, 8);
      float mu = a * (1.0f / 128.0f);
      float var = bq * (1.0f / 128.0f) - mu * mu;
      s1[r] = mu;
      s2[r] = rsqrtf(var + 1e-5f);
    }
#pragma unroll
    for (int ct = 0; ct < 8; ++ct) {
      int col = ct * 16 + m;
      float gm = gamma[col], bt = beta[col];
#pragma unroll
      for (int r = 0; r < 4; ++r) {
        int row = r0 + q * 4 + r;
        float hh = gelu((acc[ct][r] - s1[r]) * s2[r] * gm + bt);
        ah_w[(size_t)row * AHS + 128 + col] = f2bf(hh);
      }
    }
  }
}

// ---------------------------------------------------------------------------
// The megakernel: all phases, separated by software grid barriers.
__global__ __launch_bounds__(256, 1) void k_mega(
    const float* __restrict__ elements, const float* __restrict__ ln_gamma,
    const float* __restrict__ ln_beta, const float* __restrict__ w_nei,
    const float* __restrict__ b_nei, const float* __restrict__ w_root,
    const int* __restrict__ srcv, const int* __restrict__ dstv, int E,
    float* __restrict__ x, int* s0a, int* s1a, float* lvl4, float* sroot,
    unsigned short* wf, unsigned short* ah, int* bar) {
  __shared__ __align__(16) char smem[65536];
  int bid = blockIdx.x, tid = threadIdx.x;

  // ---- P0: CSR bounds + weight repack ----
  {
    int gi = bid * 256 + tid;
    if (gi < BATCH) { s0a[gi * NN] = 0; s1a[gi * NN] = 0; }
    for (int i = gi; i < E; i += NB * 256) {
      int dv = dstv[i];
      if (i == 0 || dstv[i - 1] != dv) s0a[dv] = i;
      if (i == E - 1 || dstv[i + 1] != dv) s1a[dv] = i + 1;
    }
    if (gi < 8192) {
      int l = gi >> 12, idx = gi & 4095;
      int lane = idx & 63, ct = (idx >> 6) & 7, kc = idx >> 9;
      int n = ct * 16 + (lane & 15);
      int k = kc * 32 + (lane >> 4) * 8;
      const float* w = (k < 128) ? (w_nei + (size_t)l * DD * DD)
                                 : (w_root + (size_t)l * DD * DD);
      int kk = k & 127;
      unsigned short* o = wf + (size_t)l * 32768 + (size_t)idx * 8;
#pragma unroll
      for (int j = 0; j < 8; ++j) o[j] = f2bf(w[(size_t)(kk + j) * DD + n]);
    }
  }
  gbar(bar, 0);

  // ---- P1: tree + layer-0 LN (depth>=4) ----
  if (bid < 128)
    ph_tree(smem, bid, elements, x, lvl4, ah, ln_gamma, ln_beta);
  gbar(bar, 1);

  // ---- P2: top (blocks 0-7) || aggsub L0 (blocks 8-135) ----
  if (bid < 8)
    ph_top(smem, bid, lvl4, x, ah, ln_gamma, ln_beta);
  else if (bid < 136)
    ph_aggsub(smem, bid - 8, ah, s0a, s1a, sroot);
  gbar(bar, 2);

  // ---- P3: leafagg L0 (all) + topfin L0 (blocks 0-7) ----
  ph_leafagg(smem, bid, srcv, s0a, s1a, ah);
  if (bid < 8 && tid < 128) ph_topfin(bid, sroot, s0a, s1a, ah);
  gbar(bar, 3);

  // ---- P4: gemm L0 + fused LN(L1) -> h' ----
  ph_gemm(bid, ah, wf, b_nei, x, ln_gamma + DD, ln_beta + DD, ah, 1);
  gbar(bar, 4);

  // ---- P5: aggsub L1 (blocks 0-127) ----
  if (bid < 128)
    ph_aggsub(smem, bid, ah, s0a, s1a, sroot);
  gbar(bar, 5);

  // ---- P6: leafagg L1 (all) + topfin L1 (blocks 0-7) ----
  ph_leafagg(smem, bid, srcv, s0a, s1a, ah);
  if (bid < 8 && tid < 128) ph_topfin(bid, sroot, s0a, s1a, ah);
  gbar(bar, 6);

  // ---- P7: gemm L1 ----
  ph_gemm(bid, ah, wf + 32768, b_nei + DD, x, ln_gamma, ln_beta, ah, 0);
}

// ---------------------------------------------------------------------------
extern "C" void kernel_launch(void* const* d_in, const int* in_sizes, int n_in,
                              void* d_out, int out_size, void* d_ws, size_t ws_size,
                              hipStream_t stream) {
  const float* elements = (const float*)d_in[0];
  const float* ln_gamma = (const float*)d_in[1];
  const float* ln_beta  = (const float*)d_in[2];
  const float* w_nei    = (const float*)d_in[3];
  const float* b_nei    = (const float*)d_in[4];
  const float* w_root   = (const float*)d_in[5];
  const int*   edge     = (const int*)d_in[6];
  int E = in_sizes[6] / 2;
  const int* srcv = edge;
  const int* dstv = edge + E;
  float* x = (float*)d_out;

  char* ws = (char*)d_ws;
  int*            bar   = (int*)ws;                         // 4 KB (7 barriers)
  int*            s0    = (int*)(ws + 65536);               // 64 KB
  int*            s1    = (int*)(ws + 131072);              // 64 KB
  float*          lvl4  = (float*)(ws + 196608);            // 64 KB
  float*          sroot = (float*)(ws + 262144);            // 64 KB
  unsigned short* wf    = (unsigned short*)(ws + 327680);   // 128 KB
  unsigned short* ah    = (unsigned short*)(ws + 458752);   // 8 MB

  hipMemsetAsync(bar, 0, 4096, stream);
  k_mega<<<dim3(NB), dim3(256), 0, stream>>>(
      elements, ln_gamma, ln_beta, w_nei, b_nei, w_root,
      srcv, dstv, E, x, s0, s1, lvl4, sroot, wf, ah, bar);
}

// Round 6
// 245.958 us; speedup vs baseline: 1.4340x; 1.4340x over previous
//
#include <hip/hip_runtime.h>
#include <hip/hip_bf16.h>

// Problem constants (fixed by the reference file)
#define LEAFN 1024
#define NN    2048            // nodes per batch incl. global node 0
#define BATCH 8
#define DD    128
#define ROWS  (BATCH*NN)      // 16384
#define AHS   256             // ah row stride: [agg(128) | h(128)] bf16
#define NB    256             // megakernel grid size (blocks)

// ln(10000)/32
#define LOG1E4_OVER_32 0.28782313662425575f

typedef __bf16 bf16x8 __attribute__((ext_vector_type(8)));
typedef float  floatx4 __attribute__((ext_vector_type(4)));

__device__ __forceinline__ float bf2f(unsigned short u) {
  return __uint_as_float(((unsigned)u) << 16);
}
__device__ __forceinline__ unsigned short f2bf(float f) {
  unsigned u = __float_as_uint(f);
  u += 0x7FFFu + ((u >> 16) & 1u);          // round-to-nearest-even
  return (unsigned short)(u >> 16);
}
__device__ __forceinline__ float gelu(float v) {
  return 0.5f * v * (1.0f + erff(v * 0.70710678118f));
}
__device__ __forceinline__ void cvt8(uint4 u, float* f) {
  f[0] = __uint_as_float(u.x << 16); f[1] = __uint_as_float(u.x & 0xffff0000u);
  f[2] = __uint_as_float(u.y << 16); f[3] = __uint_as_float(u.y & 0xffff0000u);
  f[4] = __uint_as_float(u.z << 16); f[5] = __uint_as_float(u.z & 0xffff0000u);
  f[6] = __uint_as_float(u.w << 16); f[7] = __uint_as_float(u.w & 0xffff0000u);
}

__device__ __forceinline__ float enc_val(int node, int d) {
  float hp, vp;
  if (node == 0) { hp = -0.5f; vp = -1.0f; }
  else {
    int v = 31 - __clz(node);
    hp = (float)(node - (1 << v));
    vp = (float)v;
  }
  float pos = (d < 64) ? hp : vp;
  int i = ((d < 64) ? d : (d - 64)) >> 1;
  float inv = expf(-(float)i * LOG1E4_OVER_32);
  float ang = pos * inv;
  return (d & 1) ? cosf(ang) : sinf(ang);
}

// ---------------------------------------------------------------------------
// Two-level grid barrier: 8 groups x 32 blocks (group = bid&7, XCD-affine on
// round-robin dispatch; correctness does not depend on the mapping). Layout
// per barrier idx (1024 ints): [g*32] group counters, [256+g*32] go flags,
// [512] global counter. All counters zeroed by hipMemsetAsync pre-launch.
// One __threadfence() pair per block = the minimum for cross-XCD coherence.
__device__ __forceinline__ void gbar(int* bar, int idx) {
  __syncthreads();
  if (threadIdx.x == 0) {
    int* base = bar + idx * 1024;
    int g = blockIdx.x & 7;
    __threadfence();                           // release: waitcnt + L2 wb
    if (__hip_atomic_fetch_add(base + g * 32, 1, __ATOMIC_RELAXED,
                               __HIP_MEMORY_SCOPE_AGENT) == 31) {
      // last arriver in group -> group leader
      if (__hip_atomic_fetch_add(base + 512, 1, __ATOMIC_RELAXED,
                                 __HIP_MEMORY_SCOPE_AGENT) == 7) {
        // last group -> global leader releases everyone
#pragma unroll
        for (int j = 0; j < 8; ++j)
          __hip_atomic_store(base + 256 + j * 32, 1, __ATOMIC_RELAXED,
                             __HIP_MEMORY_SCOPE_AGENT);
      }
    }
    while (!__hip_atomic_load(base + 256 + g * 32, __ATOMIC_RELAXED,
                              __HIP_MEMORY_SCOPE_AGENT))
      __builtin_amdgcn_s_sleep(8);
    __threadfence();                           // acquire: L2 inv
  }
  __syncthreads();
}

// ---------------------------------------------------------------------------
// Phase: tree build + layer-0 LN/GELU for depth>=4 nodes. blk in [0,128).
__device__ __forceinline__ void ph_tree(char* smemc, int blk,
                                        const float* __restrict__ elements,
                                        float* __restrict__ x,
                                        float* __restrict__ lvl4,
                                        unsigned short* __restrict__ ah,
                                        const float* __restrict__ gamma,
                                        const float* __restrict__ beta) {
  float* sm = (float*)smemc;                  // 127*128 floats = 63.5 KB
  int tid = threadIdx.x;
  int b = blk >> 4, s = blk & 15;
  const float4* src = (const float4*)(elements + (size_t)(b * LEAFN + s * 64) * DD);
  for (int i = tid; i < 2048; i += 256) {
    int f = i * 4;
    int j = f >> 7, d = f & 127;
    *(float4*)&sm[(63 + j) * DD + d] = src[i];
  }
  __syncthreads();
  for (int lv = 5; lv >= 0; --lv) {
    int nodes = 1 << lv;
    for (int idx = tid; idx < nodes * DD; idx += 256) {
      int k = nodes + (idx >> 7);
      int d = idx & 127;
      sm[(k - 1) * DD + d] = 0.5f * (sm[(2 * k - 1) * DD + d] + sm[(2 * k) * DD + d]);
    }
    __syncthreads();
  }
  if (tid < DD) lvl4[(b * 16 + s) * DD + tid] = sm[tid];
  __syncthreads();
  for (int idx = tid; idx < 127 * DD; idx += 256) {
    int k = (idx >> 7) + 1;
    int d = idx & 127;
    int lv = 31 - __clz(k);
    int g = ((16 + s) << lv) | (k - (1 << lv));
    float xv = sm[idx] + enc_val(g, d);
    x[((size_t)(b * NN + g)) * DD + d] = xv;
    sm[idx] = xv;
  }
  __syncthreads();
  int sub = tid & 7, dp = sub * 16;
  float gm[16], bt[16];
#pragma unroll
  for (int j = 0; j < 16; ++j) { gm[j] = gamma[dp + j]; bt[j] = beta[dp + j]; }
  for (int rr = tid >> 3; rr < 127; rr += 32) {
    float v[16], s1 = 0.f, s2 = 0.f;
#pragma unroll
    for (int j = 0; j < 16; ++j) { v[j] = sm[rr * DD + dp + j]; s1 += v[j]; s2 += v[j] * v[j]; }
    s1 += __shfl_xor(s1, 1); s2 += __shfl_xor(s2, 1);
    s1 += __shfl_xor(s1, 2); s2 += __shfl_xor(s2, 2);
    s1 += __shfl_xor(s1, 4); s2 += __shfl_xor(s2, 4);
    float mu = s1 * (1.0f / 128.0f);
    float var = s2 * (1.0f / 128.0f) - mu * mu;
    float rinv = rsqrtf(var + 1e-5f);
    int k = rr + 1, lv = 31 - __clz(k);
    int g = ((16 + s) << lv) | (k - (1 << lv));
    unsigned short o[16];
#pragma unroll
    for (int j = 0; j < 16; ++j)
      o[j] = f2bf(gelu((v[j] - mu) * rinv * gm[j] + bt[j]));
    unsigned short* dst = &ah[(size_t)(b * NN + g) * AHS + 128 + dp];
#pragma unroll
    for (int j = 0; j < 4; ++j) *(ushort4*)&dst[j * 4] = *(ushort4*)&o[j * 4];
  }
}

// ---------------------------------------------------------------------------
// Phase: top nodes 0..15 of batch b: finish tree, write x and layer-0 h.
__device__ __forceinline__ void ph_top(char* smemc, int b,
                                       const float* __restrict__ lvl4,
                                       float* __restrict__ x,
                                       unsigned short* __restrict__ ah,
                                       const float* __restrict__ gamma,
                                       const float* __restrict__ beta) {
  float (*xs)[DD] = (float(*)[DD])smemc;      // 16*128 floats = 8 KB
  int tid = threadIdx.x;
  if (tid < 128) {
    int d = tid;
    float v[16];
    for (int j = 0; j < 16; ++j) v[j] = lvl4[(b * 16 + j) * DD + d];
    for (int j = 0; j < 8; ++j) v[j] = 0.5f * (v[2 * j] + v[2 * j + 1]);
    for (int j = 0; j < 8; ++j) xs[8 + j][d] = v[j] + enc_val(8 + j, d);
    for (int j = 0; j < 4; ++j) v[j] = 0.5f * (v[2 * j] + v[2 * j + 1]);
    for (int j = 0; j < 4; ++j) xs[4 + j][d] = v[j] + enc_val(4 + j, d);
    for (int j = 0; j < 2; ++j) v[j] = 0.5f * (v[2 * j] + v[2 * j + 1]);
    for (int j = 0; j < 2; ++j) xs[2 + j][d] = v[j] + enc_val(2 + j, d);
    v[0] = 0.5f * (v[0] + v[1]);
    xs[1][d] = v[0] + enc_val(1, d);
    xs[0][d] = -1.0f + enc_val(0, d);
    for (int j = 0; j < 16; ++j) x[((size_t)(b * NN + j)) * DD + d] = xs[j][d];
  }
  __syncthreads();
  if (tid < 128) {
    int rr = tid >> 3, sub = tid & 7, dp = sub * 16;
    float w[16], s1 = 0.f, s2 = 0.f;
#pragma unroll
    for (int j = 0; j < 16; ++j) { w[j] = xs[rr][dp + j]; s1 += w[j]; s2 += w[j] * w[j]; }
    s1 += __shfl_xor(s1, 1); s2 += __shfl_xor(s2, 1);
    s1 += __shfl_xor(s1, 2); s2 += __shfl_xor(s2, 2);
    s1 += __shfl_xor(s1, 4); s2 += __shfl_xor(s2, 4);
    float mu = s1 * (1.0f / 128.0f);
    float var = s2 * (1.0f / 128.0f) - mu * mu;
    float rinv = rsqrtf(var + 1e-5f);
    unsigned short o[16];
#pragma unroll
    for (int j = 0; j < 16; ++j)
      o[j] = f2bf(gelu((w[j] - mu) * rinv * gamma[dp + j] + beta[dp + j]));
    unsigned short* dst = &ah[(size_t)(b * NN + rr) * AHS + 128 + dp];
#pragma unroll
    for (int j = 0; j < 4; ++j) *(ushort4*)&dst[j * 4] = *(ushort4*)&o[j * 4];
  }
}

// ---------------------------------------------------------------------------
// Phase: subtree sums for internal nodes depth 4..9, sb in [0,128).
__device__ __forceinline__ void ph_aggsub(char* smemc, int sb,
                                          unsigned short* ah,
                                          const int* __restrict__ s0a,
                                          const int* __restrict__ s1a,
                                          float* __restrict__ sroot) {
  floatx4 (*S)[32] = (floatx4(*)[32])smemc;   // 64*32*16 = 32 KB
  int tid = threadIdx.x;
  int b = sb >> 4, s = sb & 15;

  for (int idx = tid; idx < 32 * 32; idx += 256) {
    int k = 32 + (idx >> 5), q = idx & 31;
    int c = (16 + s) * 64 + (2 * k - 64);
    size_t a0 = (size_t)(b * NN + c) * AHS + 128 + q * 4;
    ushort4 u0 = *(const ushort4*)&ah[a0];
    ushort4 u1 = *(const ushort4*)&ah[a0 + AHS];
    floatx4 v;
    v[0] = bf2f(u0.x) + bf2f(u1.x);
    v[1] = bf2f(u0.y) + bf2f(u1.y);
    v[2] = bf2f(u0.z) + bf2f(u1.z);
    v[3] = bf2f(u0.w) + bf2f(u1.w);
    S[k][q] = v;
    int g = (16 + s) * 32 + (k - 32);
    int r = b * NN + g;
    float inv = 1.0f / (float)max(s1a[r] - s0a[r], 1);
    ushort4 o;
    o.x = f2bf(v[0] * inv); o.y = f2bf(v[1] * inv);
    o.z = f2bf(v[2] * inv); o.w = f2bf(v[3] * inv);
    *(ushort4*)&ah[(size_t)r * AHS + q * 4] = o;
  }
  __syncthreads();
  for (int lv = 4; lv >= 0; --lv) {
    int nk = 1 << lv;
    for (int idx = tid; idx < nk * 32; idx += 256) {
      int k = nk + (idx >> 5), q = idx & 31;
      int c = ((16 + s) << (lv + 1)) | (2 * k - 2 * nk);
      size_t a0 = (size_t)(b * NN + c) * AHS + 128 + q * 4;
      ushort4 u0 = *(const ushort4*)&ah[a0];
      ushort4 u1 = *(const ushort4*)&ah[a0 + AHS];
      floatx4 sc0 = S[2 * k][q], sc1 = S[2 * k + 1][q];
      floatx4 v;
      v[0] = bf2f(u0.x) + bf2f(u1.x) + sc0[0] + sc1[0];
      v[1] = bf2f(u0.y) + bf2f(u1.y) + sc0[1] + sc1[1];
      v[2] = bf2f(u0.z) + bf2f(u1.z) + sc0[2] + sc1[2];
      v[3] = bf2f(u0.w) + bf2f(u1.w) + sc0[3] + sc1[3];
      S[k][q] = v;
      int g = ((16 + s) << lv) | (k - nk);
      int r = b * NN + g;
      float inv = 1.0f / (float)max(s1a[r] - s0a[r], 1);
      ushort4 o;
      o.x = f2bf(v[0] * inv); o.y = f2bf(v[1] * inv);
      o.z = f2bf(v[2] * inv); o.w = f2bf(v[3] * inv);
      *(ushort4*)&ah[(size_t)r * AHS + q * 4] = o;
    }
    __syncthreads();
  }
  for (int q = tid; q < 32; q += 256)
    ((floatx4*)sroot)[(size_t)(b * 16 + s) * 32 + q] = S[1][q];
}

// ---------------------------------------------------------------------------
// Phase: leaf-row gather with per-level LDS window cache. bid in [0,256).
#define SLACK 10
#define CACHE_ROWS 220
#define CSTRIDE 136
__device__ __forceinline__ void ph_leafagg(char* smemc, int bid,
                                           const int* __restrict__ src,
                                           const int* __restrict__ s0a,
                                           const int* __restrict__ s1a,
                                           unsigned short* ah) {
  unsigned short* cache = (unsigned short*)smemc;  // 220*136*2 = 58.5 KB
  int tid = threadIdx.x;
  int b = bid >> 5, jb = bid & 31;
  int li0 = jb * 32;
  int g0 = 1024 + li0, g1 = g0 + 31;

  int lo[11], wd[11], off[11];
  int acc_off = 0;
  for (int cd = 10; cd >= 1; --cd) {
    int a0 = g0 >> (10 - cd), a1 = g1 >> (10 - cd);
    int l = a0 - SLACK, hgh = a1 + SLACK;
    int lvlo = 1 << cd, lvhi = (2 << cd) - 1;
    l = l < lvlo ? lvlo : l;
    hgh = hgh > lvhi ? lvhi : hgh;
    int w = hgh - l + 1;
    if (acc_off + w > CACHE_ROWS) w = CACHE_ROWS - acc_off;
    if (w < 0) w = 0;
    lo[cd] = l; wd[cd] = w; off[cd] = acc_off; acc_off += w;
  }
  for (int cd = 10; cd >= 1; --cd) {
    int w = wd[cd];
    for (int t = tid; t < w * 16; t += 256) {
      int row = t >> 4, seg = t & 15;
      *(uint4*)&cache[(off[cd] + row) * CSTRIDE + seg * 8] =
          *(const uint4*)&ah[(size_t)(b * NN + lo[cd] + row) * AHS + 128 + seg * 8];
    }
  }
  __syncthreads();

  int leaf = li0 + (tid >> 3);
  int dp = (tid & 7) * 16;
  int r = b * NN + 1024 + leaf;
  int e0 = s0a[r], e1 = s1a[r];
  float acc[16];
#pragma unroll
  for (int j = 0; j < 16; ++j) acc[j] = 0.f;
  for (int e = e0; e < e1; ++e) {
    int g = src[e] - b * NN;
    int lv = 31 - __clz(g);
    int idx = g - lo[lv];
    float f[16];
    if ((unsigned)idx < (unsigned)wd[lv]) {
      const unsigned short* p = &cache[(off[lv] + idx) * CSTRIDE + dp];
      cvt8(*(const uint4*)p, f);
      cvt8(*(const uint4*)(p + 8), f + 8);
    } else {
      const unsigned short* p = &ah[(size_t)(b * NN + g) * AHS + 128 + dp];
      cvt8(*(const uint4*)p, f);
      cvt8(*(const uint4*)(p + 8), f + 8);
    }
#pragma unroll
    for (int j = 0; j < 16; ++j) acc[j] += f[j];
  }
  float inv = 1.0f / (float)max(e1 - e0, 1);
  unsigned short o[16];
#pragma unroll
  for (int j = 0; j < 16; ++j) o[j] = f2bf(acc[j] * inv);
  unsigned short* dst = &ah[(size_t)r * AHS + dp];
#pragma unroll
  for (int j = 0; j < 4; ++j) *(ushort4*)&dst[j * 4] = *(ushort4*)&o[j * 4];
}

// ---------------------------------------------------------------------------
// Finish agg for nodes 0..15 of batch b (threads 0..127 only).
__device__ __forceinline__ void ph_topfin(int b,
                                          const float* __restrict__ sroot,
                                          const int* __restrict__ s0a,
                                          const int* __restrict__ s1a,
                                          unsigned short* ah) {
  int d = threadIdx.x;
  float S16[16], h16[16], Sv[16];
#pragma unroll
  for (int j = 0; j < 16; ++j) S16[j] = sroot[(size_t)(b * 16 + j) * DD + d];
#pragma unroll
  for (int j = 0; j < 16; ++j)
    h16[j] = bf2f(ah[(size_t)(b * NN + 16 + j) * AHS + 128 + d]);
#pragma unroll
  for (int k = 8; k < 16; ++k)
    Sv[k] = h16[2 * k - 16] + h16[2 * k - 15] + S16[2 * k - 16] + S16[2 * k - 15];
#pragma unroll
  for (int k = 7; k >= 1; --k)
    Sv[k] = bf2f(ah[(size_t)(b * NN + 2 * k) * AHS + 128 + d]) +
            bf2f(ah[(size_t)(b * NN + 2 * k + 1) * AHS + 128 + d]) +
            Sv[2 * k] + Sv[2 * k + 1];
#pragma unroll
  for (int k = 1; k < 16; ++k) {
    int r = b * NN + k;
    float inv = 1.0f / (float)max(s1a[r] - s0a[r], 1);
    ah[(size_t)r * AHS + d] = f2bf(Sv[k] * inv);
  }
  ah[(size_t)(b * NN) * AHS + d] = f2bf(0.0f);
}

// ---------------------------------------------------------------------------
// Phase: x += [agg|h] @ [Wn;Wr] + bias (bf16 MFMA), 64 rows/block, optional
// fused next-layer LN+GELU writing h'. Blocks with bid%32==0 first finish
// agg rows 0..15 of their batch (topfin) block-locally.
__device__ __forceinline__ void ph_gemm(int bid,
                                        unsigned short* ah,
                                        const unsigned short* __restrict__ wfl,
                                        const float* __restrict__ bn,
                                        float* __restrict__ x,
                                        const float* __restrict__ gamma,
                                        const float* __restrict__ beta,
                                        const float* __restrict__ sroot,
                                        const int* __restrict__ s0a,
                                        const int* __restrict__ s1a,
                                        int write_h) {
  if ((bid & 31) == 0) {
    if (threadIdx.x < 128) ph_topfin(bid >> 5, sroot, s0a, s1a, ah);
    __syncthreads();
  }
  int wave = threadIdx.x >> 6, lane = threadIdx.x & 63;
  int r0 = bid * 64 + wave * 16;
  int m = lane & 15, q = lane >> 4;
  const bf16x8* A0 = (const bf16x8*)(ah + (size_t)(r0 + m) * AHS + q * 8);
  const bf16x8* B  = (const bf16x8*)wfl + lane;
  floatx4 acc[8];
#pragma unroll
  for (int ct = 0; ct < 8; ++ct) acc[ct] = (floatx4){0.f, 0.f, 0.f, 0.f};

#pragma unroll
  for (int kc = 0; kc < 8; ++kc) {
    bf16x8 a0 = A0[kc * 4];
#pragma unroll
    for (int ct = 0; ct < 8; ++ct) {
      bf16x8 bb = B[(kc * 8 + ct) * 64];
      acc[ct] = __builtin_amdgcn_mfma_f32_16x16x32_bf16(a0, bb, acc[ct], 0, 0, 0);
    }
  }
  float s1[4] = {0.f, 0.f, 0.f, 0.f}, s2[4] = {0.f, 0.f, 0.f, 0.f};
#pragma unroll
  for (int ct = 0; ct < 8; ++ct) {
    int col = ct * 16 + m;
    float bias = bn[col];
#pragma unroll
    for (int r = 0; r < 4; ++r) {
      int row = r0 + q * 4 + r;
      float v = x[(size_t)row * DD + col] + acc[ct][r] + bias;
      x[(size_t)row * DD + col] = v;
      acc[ct][r] = v;
      s1[r] += v; s2[r] += v * v;
    }
  }
  if (write_h) {
#pragma unroll
    for (int r = 0; r < 4; ++r) {
      float a = s1[r], bq = s2[r];
      a += __shfl_xor(a, 1); bq += __shfl_xor(bq, 1);
      a += __shfl_xor(a, 2); bq += __shfl_xor(bq, 2);
      a += __shfl_xor(a, 4); bq += __shfl_xor(bq, 4);
      a += __shfl_xor(a, 8); bq += __shfl_xor(bq, 8);
      float mu = a * (1.0f / 128.0f);
      float var = bq * (1.0f / 128.0f) - mu * mu;
      s1[r] = mu;
      s2[r] = rsqrtf(var + 1e-5f);
    }
#pragma unroll
    for (int ct = 0; ct < 8; ++ct) {
      int col = ct * 16 + m;
      float gm = gamma[col], bt = beta[col];
#pragma unroll
      for (int r = 0; r < 4; ++r) {
        int row = r0 + q * 4 + r;
        float hh = gelu((acc[ct][r] - s1[r]) * s2[r] * gm + bt);
        ah[(size_t)row * AHS + 128 + col] = f2bf(hh);
      }
    }
  }
}

// ---------------------------------------------------------------------------
// The megakernel: 6 phases, 5 grid barriers.
__global__ __launch_bounds__(256, 1) void k_mega(
    const float* __restrict__ elements, const float* __restrict__ ln_gamma,
    const float* __restrict__ ln_beta, const float* __restrict__ w_nei,
    const float* __restrict__ b_nei, const float* __restrict__ w_root,
    const int* __restrict__ srcv, const int* __restrict__ dstv, int E,
    float* __restrict__ x, int* s0a, int* s1a, float* lvl4, float* sroot,
    unsigned short* wf, unsigned short* ah, int* bar) {
  __shared__ __align__(16) char smem[65536];
  int bid = blockIdx.x, tid = threadIdx.x;

  // ---- P0: tree+LN0 (0-127) || CSR bounds (128-223) || repack (224-255) ----
  if (bid < 128) {
    ph_tree(smem, bid, elements, x, lvl4, ah, ln_gamma, ln_beta);
  } else if (bid < 224) {
    int gi = (bid - 128) * 256 + tid;          // 24576 threads
    if (gi < BATCH) { s0a[gi * NN] = 0; s1a[gi * NN] = 0; }
    for (int i = gi; i < E; i += 96 * 256) {
      int dv = dstv[i];
      if (i == 0 || dstv[i - 1] != dv) s0a[dv] = i;
      if (i == E - 1 || dstv[i + 1] != dv) s1a[dv] = i + 1;
    }
  } else {
    int gi = (bid - 224) * 256 + tid;          // 8192 = 2 layers x 4096 frags
    int l = gi >> 12, idx = gi & 4095;
    int lane = idx & 63, ct = (idx >> 6) & 7, kc = idx >> 9;
    int n = ct * 16 + (lane & 15);
    int k = kc * 32 + (lane >> 4) * 8;
    const float* w = (k < 128) ? (w_nei + (size_t)l * DD * DD)
                               : (w_root + (size_t)l * DD * DD);
    int kk = k & 127;
    unsigned short* o = wf + (size_t)l * 32768 + (size_t)idx * 8;
#pragma unroll
    for (int j = 0; j < 8; ++j) o[j] = f2bf(w[(size_t)(kk + j) * DD + n]);
  }
  gbar(bar, 0);

  // ---- P1: top (0-7) || aggsub L0 (8-135) ----
  if (bid < 8)
    ph_top(smem, bid, lvl4, x, ah, ln_gamma, ln_beta);
  else if (bid < 136)
    ph_aggsub(smem, bid - 8, ah, s0a, s1a, sroot);
  gbar(bar, 1);

  // ---- P2: leafagg L0 (all 256) ----
  ph_leafagg(smem, bid, srcv, s0a, s1a, ah);
  gbar(bar, 2);

  // ---- P3: gemm L0 (+topfin L0 in 8 blocks) + fused LN(L1) -> h' ----
  ph_gemm(bid, ah, wf, b_nei, x, ln_gamma + DD, ln_beta + DD,
          sroot, s0a, s1a, 1);
  gbar(bar, 3);

  // ---- P4: aggsub L1 (0-127) then leafagg L1 (all 256) ----
  if (bid < 128) {
    ph_aggsub(smem, bid, ah, s0a, s1a, sroot);
    __syncthreads();
  }
  ph_leafagg(smem, bid, srcv, s0a, s1a, ah);
  gbar(bar, 4);

  // ---- P5: gemm L1 (+topfin L1) ----
  ph_gemm(bid, ah, wf + 32768, b_nei + DD, x, ln_gamma, ln_beta,
          sroot, s0a, s1a, 0);
}

// ---------------------------------------------------------------------------
extern "C" void kernel_launch(void* const* d_in, const int* in_sizes, int n_in,
                              void* d_out, int out_size, void* d_ws, size_t ws_size,
                              hipStream_t stream) {
  const float* elements = (const float*)d_in[0];
  const float* ln_gamma = (const float*)d_in[1];
  const float* ln_beta  = (const float*)d_in[2];
  const float* w_nei    = (const float*)d_in[3];
  const float* b_nei    = (const float*)d_in[4];
  const float* w_root   = (const float*)d_in[5];
  const int*   edge     = (const int*)d_in[6];
  int E = in_sizes[6] / 2;
  const int* srcv = edge;
  const int* dstv = edge + E;
  float* x = (float*)d_out;

  char* ws = (char*)d_ws;
  int*            bar   = (int*)ws;                         // 32 KB (5 barriers)
  int*            s0    = (int*)(ws + 65536);               // 64 KB
  int*            s1    = (int*)(ws + 131072);              // 64 KB
  float*          lvl4  = (float*)(ws + 196608);            // 64 KB
  float*          sroot = (float*)(ws + 262144);            // 64 KB
  unsigned short* wf    = (unsigned short*)(ws + 327680);   // 128 KB
  unsigned short* ah    = (unsigned short*)(ws + 458752);   // 8 MB

  hipMemsetAsync(bar, 0, 32768, stream);
  k_mega<<<dim3(NB), dim3(256), 0, stream>>>(
      elements, ln_gamma, ln_beta, w_nei, b_nei, w_root,
      srcv, dstv, E, x, s0, s1, lvl4, sroot, wf, ah, bar);
}

// Round 7
// 240.792 us; speedup vs baseline: 1.4648x; 1.0215x over previous
//
#include <hip/hip_runtime.h>
#include <hip/hip_bf16.h>

// Problem constants (fixed by the reference file)
#define LEAFN 1024
#define NN    2048            // nodes per batch incl. global node 0
#define BATCH 8
#define DD    128
#define ROWS  (BATCH*NN)      // 16384
#define AHS   256             // ah row stride: [agg(128) | h(128)] bf16
#define NB    256             // megakernel grid size (blocks)
#define NT    512             // threads per block (8 waves -> 2 waves/SIMD)

// ln(10000)/32
#define LOG1E4_OVER_32 0.28782313662425575f

typedef __bf16 bf16x8 __attribute__((ext_vector_type(8)));
typedef float  floatx4 __attribute__((ext_vector_type(4)));

__device__ __forceinline__ float bf2f(unsigned short u) {
  return __uint_as_float(((unsigned)u) << 16);
}
__device__ __forceinline__ unsigned short f2bf(float f) {
  unsigned u = __float_as_uint(f);
  u += 0x7FFFu + ((u >> 16) & 1u);          // round-to-nearest-even
  return (unsigned short)(u >> 16);
}
__device__ __forceinline__ float gelu(float v) {
  return 0.5f * v * (1.0f + erff(v * 0.70710678118f));
}
__device__ __forceinline__ void cvt8(uint4 u, float* f) {
  f[0] = __uint_as_float(u.x << 16); f[1] = __uint_as_float(u.x & 0xffff0000u);
  f[2] = __uint_as_float(u.y << 16); f[3] = __uint_as_float(u.y & 0xffff0000u);
  f[4] = __uint_as_float(u.z << 16); f[5] = __uint_as_float(u.z & 0xffff0000u);
  f[6] = __uint_as_float(u.w << 16); f[7] = __uint_as_float(u.w & 0xffff0000u);
}

__device__ __forceinline__ float enc_val(int node, int d) {
  float hp, vp;
  if (node == 0) { hp = -0.5f; vp = -1.0f; }
  else {
    int v = 31 - __clz(node);
    hp = (float)(node - (1 << v));
    vp = (float)v;
  }
  float pos = (d < 64) ? hp : vp;
  int i = ((d < 64) ? d : (d - 64)) >> 1;
  float inv = expf(-(float)i * LOG1E4_OVER_32);
  float ang = pos * inv;
  return (d & 1) ? cosf(ang) : sinf(ang);
}

// ---------------------------------------------------------------------------
// Two-level grid barrier (8 groups x 32 blocks). Counters zeroed pre-launch.
__device__ __forceinline__ void gbar(int* bar, int idx) {
  __syncthreads();
  if (threadIdx.x == 0) {
    int* base = bar + idx * 1024;
    int g = blockIdx.x & 7;
    __threadfence();                           // release: waitcnt + L2 wb
    if (__hip_atomic_fetch_add(base + g * 32, 1, __ATOMIC_RELAXED,
                               __HIP_MEMORY_SCOPE_AGENT) == 31) {
      if (__hip_atomic_fetch_add(base + 512, 1, __ATOMIC_RELAXED,
                                 __HIP_MEMORY_SCOPE_AGENT) == 7) {
#pragma unroll
        for (int j = 0; j < 8; ++j)
          __hip_atomic_store(base + 256 + j * 32, 1, __ATOMIC_RELAXED,
                             __HIP_MEMORY_SCOPE_AGENT);
      }
    }
    while (!__hip_atomic_load(base + 256 + g * 32, __ATOMIC_RELAXED,
                              __HIP_MEMORY_SCOPE_AGENT))
      __builtin_amdgcn_s_sleep(2);
    __threadfence();                           // acquire: L2 inv
  }
  __syncthreads();
}

// ---------------------------------------------------------------------------
// Tree build + layer-0 LN/GELU for depth>=4 nodes. blk in [0,128), 512 thr.
__device__ __forceinline__ void ph_tree(char* smemc, int blk,
                                        const float* __restrict__ elements,
                                        float* __restrict__ x,
                                        float* __restrict__ lvl4,
                                        unsigned short* __restrict__ ah,
                                        const float* __restrict__ gamma,
                                        const float* __restrict__ beta) {
  float* sm = (float*)smemc;                  // 127*128 floats = 63.5 KB
  int tid = threadIdx.x;
  int b = blk >> 4, s = blk & 15;
  const float4* src = (const float4*)(elements + (size_t)(b * LEAFN + s * 64) * DD);
  for (int i = tid; i < 2048; i += NT) {
    int f = i * 4;
    int j = f >> 7, d = f & 127;
    *(float4*)&sm[(63 + j) * DD + d] = src[i];
  }
  __syncthreads();
  for (int lv = 5; lv >= 0; --lv) {
    int nodes = 1 << lv;
    for (int idx = tid; idx < nodes * DD; idx += NT) {
      int k = nodes + (idx >> 7);
      int d = idx & 127;
      sm[(k - 1) * DD + d] = 0.5f * (sm[(2 * k - 1) * DD + d] + sm[(2 * k) * DD + d]);
    }
    __syncthreads();
  }
  if (tid < DD) lvl4[(b * 16 + s) * DD + tid] = sm[tid];
  __syncthreads();
  for (int idx = tid; idx < 127 * DD; idx += NT) {
    int k = (idx >> 7) + 1;
    int d = idx & 127;
    int lv = 31 - __clz(k);
    int g = ((16 + s) << lv) | (k - (1 << lv));
    float xv = sm[idx] + enc_val(g, d);
    x[((size_t)(b * NN + g)) * DD + d] = xv;
    sm[idx] = xv;
  }
  __syncthreads();
  int sub = tid & 7, dp = sub * 16;
  float gm[16], bt[16];
#pragma unroll
  for (int j = 0; j < 16; ++j) { gm[j] = gamma[dp + j]; bt[j] = beta[dp + j]; }
  for (int rr = tid >> 3; rr < 127; rr += NT / 8) {
    float v[16], s1 = 0.f, s2 = 0.f;
#pragma unroll
    for (int j = 0; j < 16; ++j) { v[j] = sm[rr * DD + dp + j]; s1 += v[j]; s2 += v[j] * v[j]; }
    s1 += __shfl_xor(s1, 1); s2 += __shfl_xor(s2, 1);
    s1 += __shfl_xor(s1, 2); s2 += __shfl_xor(s2, 2);
    s1 += __shfl_xor(s1, 4); s2 += __shfl_xor(s2, 4);
    float mu = s1 * (1.0f / 128.0f);
    float var = s2 * (1.0f / 128.0f) - mu * mu;
    float rinv = rsqrtf(var + 1e-5f);
    int k = rr + 1, lv = 31 - __clz(k);
    int g = ((16 + s) << lv) | (k - (1 << lv));
    unsigned short o[16];
#pragma unroll
    for (int j = 0; j < 16; ++j)
      o[j] = f2bf(gelu((v[j] - mu) * rinv * gm[j] + bt[j]));
    unsigned short* dst = &ah[(size_t)(b * NN + g) * AHS + 128 + dp];
#pragma unroll
    for (int j = 0; j < 4; ++j) *(ushort4*)&dst[j * 4] = *(ushort4*)&o[j * 4];
  }
}

// ---------------------------------------------------------------------------
// Top nodes 0..15 of batch b: finish tree, write x and layer-0 h (tid<128).
__device__ __forceinline__ void ph_top(char* smemc, int b,
                                       const float* __restrict__ lvl4,
                                       float* __restrict__ x,
                                       unsigned short* __restrict__ ah,
                                       const float* __restrict__ gamma,
                                       const float* __restrict__ beta) {
  float (*xs)[DD] = (float(*)[DD])smemc;      // 8 KB
  int tid = threadIdx.x;
  if (tid < 128) {
    int d = tid;
    float v[16];
    for (int j = 0; j < 16; ++j) v[j] = lvl4[(b * 16 + j) * DD + d];
    for (int j = 0; j < 8; ++j) v[j] = 0.5f * (v[2 * j] + v[2 * j + 1]);
    for (int j = 0; j < 8; ++j) xs[8 + j][d] = v[j] + enc_val(8 + j, d);
    for (int j = 0; j < 4; ++j) v[j] = 0.5f * (v[2 * j] + v[2 * j + 1]);
    for (int j = 0; j < 4; ++j) xs[4 + j][d] = v[j] + enc_val(4 + j, d);
    for (int j = 0; j < 2; ++j) v[j] = 0.5f * (v[2 * j] + v[2 * j + 1]);
    for (int j = 0; j < 2; ++j) xs[2 + j][d] = v[j] + enc_val(2 + j, d);
    v[0] = 0.5f * (v[0] + v[1]);
    xs[1][d] = v[0] + enc_val(1, d);
    xs[0][d] = -1.0f + enc_val(0, d);
    for (int j = 0; j < 16; ++j) x[((size_t)(b * NN + j)) * DD + d] = xs[j][d];
  }
  __syncthreads();
  if (tid < 128) {
    int rr = tid >> 3, sub = tid & 7, dp = sub * 16;
    float w[16], s1 = 0.f, s2 = 0.f;
#pragma unroll
    for (int j = 0; j < 16; ++j) { w[j] = xs[rr][dp + j]; s1 += w[j]; s2 += w[j] * w[j]; }
    s1 += __shfl_xor(s1, 1); s2 += __shfl_xor(s2, 1);
    s1 += __shfl_xor(s1, 2); s2 += __shfl_xor(s2, 2);
    s1 += __shfl_xor(s1, 4); s2 += __shfl_xor(s2, 4);
    float mu = s1 * (1.0f / 128.0f);
    float var = s2 * (1.0f / 128.0f) - mu * mu;
    float rinv = rsqrtf(var + 1e-5f);
    unsigned short o[16];
#pragma unroll
    for (int j = 0; j < 16; ++j)
      o[j] = f2bf(gelu((w[j] - mu) * rinv * gamma[dp + j] + beta[dp + j]));
    unsigned short* dst = &ah[(size_t)(b * NN + rr) * AHS + 128 + dp];
#pragma unroll
    for (int j = 0; j < 4; ++j) *(ushort4*)&dst[j * 4] = *(ushort4*)&o[j * 4];
  }
}

// ---------------------------------------------------------------------------
// Subtree sums for internal nodes depth 4..9, sb in [0,128), 512 thr.
__device__ __forceinline__ void ph_aggsub(char* smemc, int sb,
                                          unsigned short* ah,
                                          const int* __restrict__ s0a,
                                          const int* __restrict__ s1a,
                                          float* __restrict__ sroot) {
  floatx4 (*S)[32] = (floatx4(*)[32])smemc;   // 32 KB
  int tid = threadIdx.x;
  int b = sb >> 4, s = sb & 15;

  for (int idx = tid; idx < 32 * 32; idx += NT) {
    int k = 32 + (idx >> 5), q = idx & 31;
    int c = (16 + s) * 64 + (2 * k - 64);
    size_t a0 = (size_t)(b * NN + c) * AHS + 128 + q * 4;
    ushort4 u0 = *(const ushort4*)&ah[a0];
    ushort4 u1 = *(const ushort4*)&ah[a0 + AHS];
    floatx4 v;
    v[0] = bf2f(u0.x) + bf2f(u1.x);
    v[1] = bf2f(u0.y) + bf2f(u1.y);
    v[2] = bf2f(u0.z) + bf2f(u1.z);
    v[3] = bf2f(u0.w) + bf2f(u1.w);
    S[k][q] = v;
    int g = (16 + s) * 32 + (k - 32);
    int r = b * NN + g;
    float inv = 1.0f / (float)max(s1a[r] - s0a[r], 1);
    ushort4 o;
    o.x = f2bf(v[0] * inv); o.y = f2bf(v[1] * inv);
    o.z = f2bf(v[2] * inv); o.w = f2bf(v[3] * inv);
    *(ushort4*)&ah[(size_t)r * AHS + q * 4] = o;
  }
  __syncthreads();
  for (int lv = 4; lv >= 0; --lv) {
    int nk = 1 << lv;
    for (int idx = tid; idx < nk * 32; idx += NT) {
      int k = nk + (idx >> 5), q = idx & 31;
      int c = ((16 + s) << (lv + 1)) | (2 * k - 2 * nk);
      size_t a0 = (size_t)(b * NN + c) * AHS + 128 + q * 4;
      ushort4 u0 = *(const ushort4*)&ah[a0];
      ushort4 u1 = *(const ushort4*)&ah[a0 + AHS];
      floatx4 sc0 = S[2 * k][q], sc1 = S[2 * k + 1][q];
      floatx4 v;
      v[0] = bf2f(u0.x) + bf2f(u1.x) + sc0[0] + sc1[0];
      v[1] = bf2f(u0.y) + bf2f(u1.y) + sc0[1] + sc1[1];
      v[2] = bf2f(u0.z) + bf2f(u1.z) + sc0[2] + sc1[2];
      v[3] = bf2f(u0.w) + bf2f(u1.w) + sc0[3] + sc1[3];
      S[k][q] = v;
      int g = ((16 + s) << lv) | (k - nk);
      int r = b * NN + g;
      float inv = 1.0f / (float)max(s1a[r] - s0a[r], 1);
      ushort4 o;
      o.x = f2bf(v[0] * inv); o.y = f2bf(v[1] * inv);
      o.z = f2bf(v[2] * inv); o.w = f2bf(v[3] * inv);
      *(ushort4*)&ah[(size_t)r * AHS + q * 4] = o;
    }
    __syncthreads();
  }
  for (int q = tid; q < 32; q += NT)
    ((floatx4*)sroot)[(size_t)(b * 16 + s) * 32 + q] = S[1][q];
}

// ---------------------------------------------------------------------------
// Leaf-row gather with per-level LDS window cache. bid in [0,256), 512 thr.
// If l0patch: levels 1..3 (rows 2..15) are COMPUTED locally from lvl4
// (removes dependency on ph_top running in the same phase).
#define SLACK 10
#define CACHE_ROWS 220
#define CSTRIDE 136
__device__ __forceinline__ void ph_leafagg(char* smemc, int bid,
                                           const int* __restrict__ src,
                                           const int* __restrict__ s0a,
                                           const int* __restrict__ s1a,
                                           unsigned short* ah,
                                           const float* __restrict__ lvl4,
                                           const float* __restrict__ gamma,
                                           const float* __restrict__ beta,
                                           int l0patch) {
  unsigned short* cache = (unsigned short*)smemc;  // 220*136*2 = 58.5 KB
  int tid = threadIdx.x;
  int b = bid >> 5, jb = bid & 31;
  int li0 = jb * 32;
  int g0 = 1024 + li0, g1 = g0 + 31;

  int lo[11], wd[11], off[11];
  int acc_off = 0;
  for (int cd = 10; cd >= 1; --cd) {
    int a0 = g0 >> (10 - cd), a1 = g1 >> (10 - cd);
    int l = a0 - SLACK, hgh = a1 + SLACK;
    int lvlo = 1 << cd, lvhi = (2 << cd) - 1;
    l = l < lvlo ? lvlo : l;
    hgh = hgh > lvhi ? lvhi : hgh;
    int w = hgh - l + 1;
    if (acc_off + w > CACHE_ROWS) w = CACHE_ROWS - acc_off;
    if (w < 0) w = 0;
    lo[cd] = l; wd[cd] = w; off[cd] = acc_off; acc_off += w;
  }
  int cdmin = l0patch ? 4 : 1;
  for (int cd = 10; cd >= cdmin; --cd) {
    int w = wd[cd];
    for (int t = tid; t < w * 16; t += NT) {
      int row = t >> 4, seg = t & 15;
      *(uint4*)&cache[(off[cd] + row) * CSTRIDE + seg * 8] =
          *(const uint4*)&ah[(size_t)(b * NN + lo[cd] + row) * AHS + 128 + seg * 8];
    }
  }
  if (l0patch && tid < 112) {
    // compute h rows 2..15 from lvl4 (mean of descendant level-4 feats + enc,
    // then LN+GELU). 8 threads/row x 16 dims.
    int row = 2 + (tid >> 3), sub = tid & 7, dp = sub * 16;
    int dv = 31 - __clz(row);
    int cnt = 1 << (4 - dv);
    int l4r = (row << (4 - dv)) - 16;
    float v[16];
#pragma unroll
    for (int j = 0; j < 16; ++j) v[j] = 0.f;
    for (int c = 0; c < cnt; ++c) {
      const float* p = &lvl4[(size_t)(b * 16 + l4r + c) * DD + dp];
#pragma unroll
      for (int j = 0; j < 16; ++j) v[j] += p[j];
    }
    float sc = 1.0f / (float)cnt;
    float s1 = 0.f, s2 = 0.f;
#pragma unroll
    for (int j = 0; j < 16; ++j) {
      v[j] = v[j] * sc + enc_val(row, dp + j);
      s1 += v[j]; s2 += v[j] * v[j];
    }
    s1 += __shfl_xor(s1, 1); s2 += __shfl_xor(s2, 1);
    s1 += __shfl_xor(s1, 2); s2 += __shfl_xor(s2, 2);
    s1 += __shfl_xor(s1, 4); s2 += __shfl_xor(s2, 4);
    float mu = s1 * (1.0f / 128.0f);
    float var = s2 * (1.0f / 128.0f) - mu * mu;
    float rinv = rsqrtf(var + 1e-5f);
    unsigned short o[16];
#pragma unroll
    for (int j = 0; j < 16; ++j)
      o[j] = f2bf(gelu((v[j] - mu) * rinv * gamma[dp + j] + beta[dp + j]));
    unsigned short* dst = &cache[(off[dv] + (row - lo[dv])) * CSTRIDE + dp];
#pragma unroll
    for (int j = 0; j < 4; ++j) *(ushort4*)&dst[j * 4] = *(ushort4*)&o[j * 4];
  }
  __syncthreads();

  int leaf = li0 + (tid >> 4);
  int dp = (tid & 15) * 8;
  int r = b * NN + 1024 + leaf;
  int e0 = s0a[r], e1 = s1a[r];
  float acc[8];
#pragma unroll
  for (int j = 0; j < 8; ++j) acc[j] = 0.f;
  for (int e = e0; e < e1; ++e) {
    int g = src[e] - b * NN;
    int lv = 31 - __clz(g);
    int idx = g - lo[lv];
    uint4 u;
    if ((unsigned)idx < (unsigned)wd[lv])
      u = *(const uint4*)&cache[(off[lv] + idx) * CSTRIDE + dp];
    else
      u = *(const uint4*)&ah[(size_t)(b * NN + g) * AHS + 128 + dp];
    float f[8];
    cvt8(u, f);
#pragma unroll
    for (int j = 0; j < 8; ++j) acc[j] += f[j];
  }
  float inv = 1.0f / (float)max(e1 - e0, 1);
  unsigned short o[8];
#pragma unroll
  for (int j = 0; j < 8; ++j) o[j] = f2bf(acc[j] * inv);
  unsigned short* dst = &ah[(size_t)r * AHS + dp];
  *(ushort4*)&dst[0] = *(ushort4*)&o[0];
  *(ushort4*)&dst[4] = *(ushort4*)&o[4];
}

// ---------------------------------------------------------------------------
// Finish agg for nodes 0..15 of batch b (threads 0..127 only).
__device__ __forceinline__ void ph_topfin(int b,
                                          const float* __restrict__ sroot,
                                          const int* __restrict__ s0a,
                                          const int* __restrict__ s1a,
                                          unsigned short* ah) {
  int d = threadIdx.x;
  float S16[16], h16[16], Sv[16];
#pragma unroll
  for (int j = 0; j < 16; ++j) S16[j] = sroot[(size_t)(b * 16 + j) * DD + d];
#pragma unroll
  for (int j = 0; j < 16; ++j)
    h16[j] = bf2f(ah[(size_t)(b * NN + 16 + j) * AHS + 128 + d]);
#pragma unroll
  for (int k = 8; k < 16; ++k)
    Sv[k] = h16[2 * k - 16] + h16[2 * k - 15] + S16[2 * k - 16] + S16[2 * k - 15];
#pragma unroll
  for (int k = 7; k >= 1; --k)
    Sv[k] = bf2f(ah[(size_t)(b * NN + 2 * k) * AHS + 128 + d]) +
            bf2f(ah[(size_t)(b * NN + 2 * k + 1) * AHS + 128 + d]) +
            Sv[2 * k] + Sv[2 * k + 1];
#pragma unroll
  for (int k = 1; k < 16; ++k) {
    int r = b * NN + k;
    float inv = 1.0f / (float)max(s1a[r] - s0a[r], 1);
    ah[(size_t)r * AHS + d] = f2bf(Sv[k] * inv);
  }
  ah[(size_t)(b * NN) * AHS + d] = f2bf(0.0f);
}

// ---------------------------------------------------------------------------
// x += [agg|h] @ [Wn;Wr] + bias (bf16 MFMA). bid in [0,128), 512 thr =
// 8 waves x 16 rows = 128 rows/block. Optional fused next-layer LN+GELU.
__device__ __forceinline__ void ph_gemm(int bid,
                                        unsigned short* ah,
                                        const unsigned short* __restrict__ wfl,
                                        const float* __restrict__ bn,
                                        float* __restrict__ x,
                                        const float* __restrict__ gamma,
                                        const float* __restrict__ beta,
                                        const float* __restrict__ sroot,
                                        const int* __restrict__ s0a,
                                        const int* __restrict__ s1a,
                                        int write_h) {
  if ((bid & 15) == 0) {
    if (threadIdx.x < 128) ph_topfin(bid >> 4, sroot, s0a, s1a, ah);
    __syncthreads();
  }
  int wave = threadIdx.x >> 6, lane = threadIdx.x & 63;
  int r0 = bid * 128 + wave * 16;
  int m = lane & 15, q = lane >> 4;
  const bf16x8* A0 = (const bf16x8*)(ah + (size_t)(r0 + m) * AHS + q * 8);
  const bf16x8* B  = (const bf16x8*)wfl + lane;
  floatx4 acc[8];
#pragma unroll
  for (int ct = 0; ct < 8; ++ct) acc[ct] = (floatx4){0.f, 0.f, 0.f, 0.f};

#pragma unroll
  for (int kc = 0; kc < 8; ++kc) {
    bf16x8 a0 = A0[kc * 4];
#pragma unroll
    for (int ct = 0; ct < 8; ++ct) {
      bf16x8 bb = B[(kc * 8 + ct) * 64];
      acc[ct] = __builtin_amdgcn_mfma_f32_16x16x32_bf16(a0, bb, acc[ct], 0, 0, 0);
    }
  }
  float s1[4] = {0.f, 0.f, 0.f, 0.f}, s2[4] = {0.f, 0.f, 0.f, 0.f};
#pragma unroll
  for (int ct = 0; ct < 8; ++ct) {
    int col = ct * 16 + m;
    float bias = bn[col];
#pragma unroll
    for (int r = 0; r < 4; ++r) {
      int row = r0 + q * 4 + r;
      float v = x[(size_t)row * DD + col] + acc[ct][r] + bias;
      x[(size_t)row * DD + col] = v;
      acc[ct][r] = v;
      s1[r] += v; s2[r] += v * v;
    }
  }
  if (write_h) {
#pragma unroll
    for (int r = 0; r < 4; ++r) {
      float a = s1[r], bq = s2[r];
      a += __shfl_xor(a, 1); bq += __shfl_xor(bq, 1);
      a += __shfl_xor(a, 2); bq += __shfl_xor(bq, 2);
      a += __shfl_xor(a, 4); bq += __shfl_xor(bq, 4);
      a += __shfl_xor(a, 8); bq += __shfl_xor(bq, 8);
      float mu = a * (1.0f / 128.0f);
      float var = bq * (1.0f / 128.0f) - mu * mu;
      s1[r] = mu;
      s2[r] = rsqrtf(var + 1e-5f);
    }
#pragma unroll
    for (int ct = 0; ct < 8; ++ct) {
      int col = ct * 16 + m;
      float gm = gamma[col], bt = beta[col];
#pragma unroll
      for (int r = 0; r < 4; ++r) {
        int row = r0 + q * 4 + r;
        float hh = gelu((acc[ct][r] - s1[r]) * s2[r] * gm + bt);
        ah[(size_t)row * AHS + 128 + col] = f2bf(hh);
      }
    }
  }
}

// ---------------------------------------------------------------------------
// The megakernel: 5 phases, 4 grid barriers.
__global__ __launch_bounds__(NT, 1) void k_mega(
    const float* __restrict__ elements, const float* __restrict__ ln_gamma,
    const float* __restrict__ ln_beta, const float* __restrict__ w_nei,
    const float* __restrict__ b_nei, const float* __restrict__ w_root,
    const int* __restrict__ srcv, const int* __restrict__ dstv, int E,
    float* __restrict__ x, int* s0a, int* s1a, float* lvl4, float* sroot,
    unsigned short* wf, unsigned short* ah, int* bar) {
  __shared__ __align__(16) char smem[65536];
  int bid = blockIdx.x, tid = threadIdx.x;

  // ---- P0: tree+LN0 (0-127) || repack (128-143) || CSR bounds (144-255) ----
  if (bid < 128) {
    ph_tree(smem, bid, elements, x, lvl4, ah, ln_gamma, ln_beta);
  } else if (bid < 144) {
    int gi = (bid - 128) * NT + tid;           // 8192 = 2 layers x 4096 frags
    int l = gi >> 12, idx = gi & 4095;
    int lane = idx & 63, ct = (idx >> 6) & 7, kc = idx >> 9;
    int n = ct * 16 + (lane & 15);
    int k = kc * 32 + (lane >> 4) * 8;
    const float* w = (k < 128) ? (w_nei + (size_t)l * DD * DD)
                               : (w_root + (size_t)l * DD * DD);
    int kk = k & 127;
    unsigned short* o = wf + (size_t)l * 32768 + (size_t)idx * 8;
#pragma unroll
    for (int j = 0; j < 8; ++j) o[j] = f2bf(w[(size_t)(kk + j) * DD + n]);
  } else {
    int gi = (bid - 144) * NT + tid;           // 57344 threads
    if (gi < BATCH) { s0a[gi * NN] = 0; s1a[gi * NN] = 0; }
    for (int i = gi; i < E; i += 112 * NT) {
      int dv = dstv[i];
      if (i == 0 || dstv[i - 1] != dv) s0a[dv] = i;
      if (i == E - 1 || dstv[i + 1] != dv) s1a[dv] = i + 1;
    }
  }
  gbar(bar, 0);

  // ---- P1: top (0-7) || aggsub L0 (8-135), then leafagg L0 (all, patched) --
  if (bid < 8)
    ph_top(smem, bid, lvl4, x, ah, ln_gamma, ln_beta);
  else if (bid < 136)
    ph_aggsub(smem, bid - 8, ah, s0a, s1a, sroot);
  __syncthreads();
  ph_leafagg(smem, bid, srcv, s0a, s1a, ah, lvl4, ln_gamma, ln_beta, 1);
  gbar(bar, 1);

  // ---- P2: gemm L0 (+topfin L0) + fused LN(L1) -> h' ----
  if (bid < 128)
    ph_gemm(bid, ah, wf, b_nei, x, ln_gamma + DD, ln_beta + DD,
            sroot, s0a, s1a, 1);
  gbar(bar, 2);

  // ---- P3: aggsub L1 (0-127), leafagg L1 (all) ----
  if (bid < 128) {
    ph_aggsub(smem, bid, ah, s0a, s1a, sroot);
    __syncthreads();
  }
  ph_leafagg(smem, bid, srcv, s0a, s1a, ah, lvl4, ln_gamma, ln_beta, 0);
  gbar(bar, 3);

  // ---- P4: gemm L1 (+topfin L1) ----
  if (bid < 128)
    ph_gemm(bid, ah, wf + 32768, b_nei + DD, x, ln_gamma, ln_beta,
            sroot, s0a, s1a, 0);
}

// ---------------------------------------------------------------------------
extern "C" void kernel_launch(void* const* d_in, const int* in_sizes, int n_in,
                              void* d_out, int out_size, void* d_ws, size_t ws_size,
                              hipStream_t stream) {
  const float* elements = (const float*)d_in[0];
  const float* ln_gamma = (const float*)d_in[1];
  const float* ln_beta  = (const float*)d_in[2];
  const float* w_nei    = (const float*)d_in[3];
  const float* b_nei    = (const float*)d_in[4];
  const float* w_root   = (const float*)d_in[5];
  const int*   edge     = (const int*)d_in[6];
  int E = in_sizes[6] / 2;
  const int* srcv = edge;
  const int* dstv = edge + E;
  float* x = (float*)d_out;

  char* ws = (char*)d_ws;
  int*            bar   = (int*)ws;                         // 16 KB (4 barriers)
  int*            s0    = (int*)(ws + 65536);               // 64 KB
  int*            s1    = (int*)(ws + 131072);              // 64 KB
  float*          lvl4  = (float*)(ws + 196608);            // 64 KB
  float*          sroot = (float*)(ws + 262144);            // 64 KB
  unsigned short* wf    = (unsigned short*)(ws + 327680);   // 128 KB
  unsigned short* ah    = (unsigned short*)(ws + 458752);   // 8 MB

  hipMemsetAsync(bar, 0, 16384, stream);
  k_mega<<<dim3(NB), dim3(NT), 0, stream>>>(
      elements, ln_gamma, ln_beta, w_nei, b_nei, w_root,
      srcv, dstv, E, x, s0, s1, lvl4, sroot, wf, ah, bar);
}

// Round 8
// 228.132 us; speedup vs baseline: 1.5460x; 1.0555x over previous
//
#include <hip/hip_runtime.h>
#include <hip/hip_bf16.h>

// Problem constants (fixed by the reference file)
#define LEAFN 1024
#define NN    2048            // nodes per batch incl. global node 0
#define BATCH 8
#define DD    128
#define ROWS  (BATCH*NN)      // 16384
#define AHS   256             // ah row stride: [agg(128) | h(128)] bf16
#define NB    256             // megakernel grid size (blocks)
#define NT    512             // threads per block (8 waves)

// ln(10000)/32
#define LOG1E4_OVER_32 0.28782313662425575f

typedef __bf16 bf16x8 __attribute__((ext_vector_type(8)));
typedef float  floatx4 __attribute__((ext_vector_type(4)));

__device__ __forceinline__ float bf2f(unsigned short u) {
  return __uint_as_float(((unsigned)u) << 16);
}
__device__ __forceinline__ unsigned short f2bf(float f) {
  unsigned u = __float_as_uint(f);
  u += 0x7FFFu + ((u >> 16) & 1u);          // round-to-nearest-even
  return (unsigned short)(u >> 16);
}
__device__ __forceinline__ float gelu(float v) {
  return 0.5f * v * (1.0f + erff(v * 0.70710678118f));
}
__device__ __forceinline__ void cvt8(uint4 u, float* f) {
  f[0] = __uint_as_float(u.x << 16); f[1] = __uint_as_float(u.x & 0xffff0000u);
  f[2] = __uint_as_float(u.y << 16); f[3] = __uint_as_float(u.y & 0xffff0000u);
  f[4] = __uint_as_float(u.z << 16); f[5] = __uint_as_float(u.z & 0xffff0000u);
  f[6] = __uint_as_float(u.w << 16); f[7] = __uint_as_float(u.w & 0xffff0000u);
}

__device__ __forceinline__ float enc_val(int node, int d) {
  float hp, vp;
  if (node == 0) { hp = -0.5f; vp = -1.0f; }
  else {
    int v = 31 - __clz(node);
    hp = (float)(node - (1 << v));
    vp = (float)v;
  }
  float pos = (d < 64) ? hp : vp;
  int i = ((d < 64) ? d : (d - 64)) >> 1;
  float inv = expf(-(float)i * LOG1E4_OVER_32);
  float ang = pos * inv;
  return (d & 1) ? cosf(ang) : sinf(ang);
}

// ---------------------------------------------------------------------------
// Per-GROUP barrier: 32 blocks of group g = bid>>5 (one batch). Counters
// zeroed pre-launch. One fence pair per block for cross-XCD coherence.
__device__ __forceinline__ void gbar(int* bar, int idx) {
  __syncthreads();
  if (threadIdx.x == 0) {
    int g = blockIdx.x >> 5;
    int* base = bar + (idx * 8 + g) * 64;
    __threadfence();                           // release: drain + L2 wb
    if (__hip_atomic_fetch_add(base, 1, __ATOMIC_RELAXED,
                               __HIP_MEMORY_SCOPE_AGENT) == 31)
      __hip_atomic_store(base + 32, 1, __ATOMIC_RELAXED,
                         __HIP_MEMORY_SCOPE_AGENT);
    while (!__hip_atomic_load(base + 32, __ATOMIC_RELAXED,
                              __HIP_MEMORY_SCOPE_AGENT))
      __builtin_amdgcn_s_sleep(2);
    __threadfence();                           // acquire: L2 inv
  }
  __syncthreads();
}

// ---------------------------------------------------------------------------
// Tree build + layer-0 LN/GELU for depth>=4 nodes. (b, s), 512 thr.
__device__ __forceinline__ void ph_tree(char* smemc, int b, int s,
                                        const float* __restrict__ elements,
                                        float* __restrict__ x,
                                        float* __restrict__ lvl4,
                                        unsigned short* __restrict__ ah,
                                        const float* __restrict__ gamma,
                                        const float* __restrict__ beta) {
  float* sm = (float*)smemc;                  // 127*128 floats = 63.5 KB
  int tid = threadIdx.x;
  const float4* src = (const float4*)(elements + (size_t)(b * LEAFN + s * 64) * DD);
  for (int i = tid; i < 2048; i += NT) {
    int f = i * 4;
    int j = f >> 7, d = f & 127;
    *(float4*)&sm[(63 + j) * DD + d] = src[i];
  }
  __syncthreads();
  for (int lv = 5; lv >= 0; --lv) {
    int nodes = 1 << lv;
    for (int idx = tid; idx < nodes * DD; idx += NT) {
      int k = nodes + (idx >> 7);
      int d = idx & 127;
      sm[(k - 1) * DD + d] = 0.5f * (sm[(2 * k - 1) * DD + d] + sm[(2 * k) * DD + d]);
    }
    __syncthreads();
  }
  if (tid < DD) lvl4[(b * 16 + s) * DD + tid] = sm[tid];
  __syncthreads();
  for (int idx = tid; idx < 127 * DD; idx += NT) {
    int k = (idx >> 7) + 1;
    int d = idx & 127;
    int lv = 31 - __clz(k);
    int g = ((16 + s) << lv) | (k - (1 << lv));
    float xv = sm[idx] + enc_val(g, d);
    x[((size_t)(b * NN + g)) * DD + d] = xv;
    sm[idx] = xv;
  }
  __syncthreads();
  int sub = tid & 7, dp = sub * 16;
  float gm[16], bt[16];
#pragma unroll
  for (int j = 0; j < 16; ++j) { gm[j] = gamma[dp + j]; bt[j] = beta[dp + j]; }
  for (int rr = tid >> 3; rr < 127; rr += NT / 8) {
    float v[16], s1 = 0.f, s2 = 0.f;
#pragma unroll
    for (int j = 0; j < 16; ++j) { v[j] = sm[rr * DD + dp + j]; s1 += v[j]; s2 += v[j] * v[j]; }
    s1 += __shfl_xor(s1, 1); s2 += __shfl_xor(s2, 1);
    s1 += __shfl_xor(s1, 2); s2 += __shfl_xor(s2, 2);
    s1 += __shfl_xor(s1, 4); s2 += __shfl_xor(s2, 4);
    float mu = s1 * (1.0f / 128.0f);
    float var = s2 * (1.0f / 128.0f) - mu * mu;
    float rinv = rsqrtf(var + 1e-5f);
    int k = rr + 1, lv = 31 - __clz(k);
    int g = ((16 + s) << lv) | (k - (1 << lv));
    unsigned short o[16];
#pragma unroll
    for (int j = 0; j < 16; ++j)
      o[j] = f2bf(gelu((v[j] - mu) * rinv * gm[j] + bt[j]));
    unsigned short* dst = &ah[(size_t)(b * NN + g) * AHS + 128 + dp];
#pragma unroll
    for (int j = 0; j < 4; ++j) *(ushort4*)&dst[j * 4] = *(ushort4*)&o[j * 4];
  }
}

// ---------------------------------------------------------------------------
// Top nodes 0..15 of batch b: finish tree, write x and layer-0 h (tid<128).
__device__ __forceinline__ void ph_top(char* smemc, int b,
                                       const float* __restrict__ lvl4,
                                       float* __restrict__ x,
                                       unsigned short* __restrict__ ah,
                                       const float* __restrict__ gamma,
                                       const float* __restrict__ beta) {
  float (*xs)[DD] = (float(*)[DD])smemc;      // 8 KB
  int tid = threadIdx.x;
  if (tid < 128) {
    int d = tid;
    float v[16];
    for (int j = 0; j < 16; ++j) v[j] = lvl4[(b * 16 + j) * DD + d];
    for (int j = 0; j < 8; ++j) v[j] = 0.5f * (v[2 * j] + v[2 * j + 1]);
    for (int j = 0; j < 8; ++j) xs[8 + j][d] = v[j] + enc_val(8 + j, d);
    for (int j = 0; j < 4; ++j) v[j] = 0.5f * (v[2 * j] + v[2 * j + 1]);
    for (int j = 0; j < 4; ++j) xs[4 + j][d] = v[j] + enc_val(4 + j, d);
    for (int j = 0; j < 2; ++j) v[j] = 0.5f * (v[2 * j] + v[2 * j + 1]);
    for (int j = 0; j < 2; ++j) xs[2 + j][d] = v[j] + enc_val(2 + j, d);
    v[0] = 0.5f * (v[0] + v[1]);
    xs[1][d] = v[0] + enc_val(1, d);
    xs[0][d] = -1.0f + enc_val(0, d);
    for (int j = 0; j < 16; ++j) x[((size_t)(b * NN + j)) * DD + d] = xs[j][d];
  }
  __syncthreads();
  if (tid < 128) {
    int rr = tid >> 3, sub = tid & 7, dp = sub * 16;
    float w[16], s1 = 0.f, s2 = 0.f;
#pragma unroll
    for (int j = 0; j < 16; ++j) { w[j] = xs[rr][dp + j]; s1 += w[j]; s2 += w[j] * w[j]; }
    s1 += __shfl_xor(s1, 1); s2 += __shfl_xor(s2, 1);
    s1 += __shfl_xor(s1, 2); s2 += __shfl_xor(s2, 2);
    s1 += __shfl_xor(s1, 4); s2 += __shfl_xor(s2, 4);
    float mu = s1 * (1.0f / 128.0f);
    float var = s2 * (1.0f / 128.0f) - mu * mu;
    float rinv = rsqrtf(var + 1e-5f);
    unsigned short o[16];
#pragma unroll
    for (int j = 0; j < 16; ++j)
      o[j] = f2bf(gelu((w[j] - mu) * rinv * gamma[dp + j] + beta[dp + j]));
    unsigned short* dst = &ah[(size_t)(b * NN + rr) * AHS + 128 + dp];
#pragma unroll
    for (int j = 0; j < 4; ++j) *(ushort4*)&dst[j * 4] = *(ushort4*)&o[j * 4];
  }
}

// ---------------------------------------------------------------------------
// Subtree sums for internal nodes depth 4..9 of (b, s), 512 thr.
__device__ __forceinline__ void ph_aggsub(char* smemc, int b, int s,
                                          unsigned short* ah,
                                          const int* __restrict__ s0a,
                                          const int* __restrict__ s1a,
                                          float* __restrict__ sroot) {
  floatx4 (*S)[32] = (floatx4(*)[32])smemc;   // 32 KB
  int tid = threadIdx.x;

  for (int idx = tid; idx < 32 * 32; idx += NT) {
    int k = 32 + (idx >> 5), q = idx & 31;
    int c = (16 + s) * 64 + (2 * k - 64);
    size_t a0 = (size_t)(b * NN + c) * AHS + 128 + q * 4;
    ushort4 u0 = *(const ushort4*)&ah[a0];
    ushort4 u1 = *(const ushort4*)&ah[a0 + AHS];
    floatx4 v;
    v[0] = bf2f(u0.x) + bf2f(u1.x);
    v[1] = bf2f(u0.y) + bf2f(u1.y);
    v[2] = bf2f(u0.z) + bf2f(u1.z);
    v[3] = bf2f(u0.w) + bf2f(u1.w);
    S[k][q] = v;
    int g = (16 + s) * 32 + (k - 32);
    int r = b * NN + g;
    float inv = 1.0f / (float)max(s1a[r] - s0a[r], 1);
    ushort4 o;
    o.x = f2bf(v[0] * inv); o.y = f2bf(v[1] * inv);
    o.z = f2bf(v[2] * inv); o.w = f2bf(v[3] * inv);
    *(ushort4*)&ah[(size_t)r * AHS + q * 4] = o;
  }
  __syncthreads();
  for (int lv = 4; lv >= 0; --lv) {
    int nk = 1 << lv;
    for (int idx = tid; idx < nk * 32; idx += NT) {
      int k = nk + (idx >> 5), q = idx & 31;
      int c = ((16 + s) << (lv + 1)) | (2 * k - 2 * nk);
      size_t a0 = (size_t)(b * NN + c) * AHS + 128 + q * 4;
      ushort4 u0 = *(const ushort4*)&ah[a0];
      ushort4 u1 = *(const ushort4*)&ah[a0 + AHS];
      floatx4 sc0 = S[2 * k][q], sc1 = S[2 * k + 1][q];
      floatx4 v;
      v[0] = bf2f(u0.x) + bf2f(u1.x) + sc0[0] + sc1[0];
      v[1] = bf2f(u0.y) + bf2f(u1.y) + sc0[1] + sc1[1];
      v[2] = bf2f(u0.z) + bf2f(u1.z) + sc0[2] + sc1[2];
      v[3] = bf2f(u0.w) + bf2f(u1.w) + sc0[3] + sc1[3];
      S[k][q] = v;
      int g = ((16 + s) << lv) | (k - nk);
      int r = b * NN + g;
      float inv = 1.0f / (float)max(s1a[r] - s0a[r], 1);
      ushort4 o;
      o.x = f2bf(v[0] * inv); o.y = f2bf(v[1] * inv);
      o.z = f2bf(v[2] * inv); o.w = f2bf(v[3] * inv);
      *(ushort4*)&ah[(size_t)r * AHS + q * 4] = o;
    }
    __syncthreads();
  }
  for (int q = tid; q < 32; q += NT)
    ((floatx4*)sroot)[(size_t)(b * 16 + s) * 32 + q] = S[1][q];
}

// ---------------------------------------------------------------------------
// Leaf-row gather with per-level LDS window cache (XOR-swizzled chunks).
// (b, jb in [0,32)), 512 thr = 32 leaves x 16 chunk-threads.
#define SLACK 10
#define CACHE_ROWS 220
#define CSTRIDE 136
__device__ __forceinline__ void ph_leafagg(char* smemc, int b, int jb,
                                           const int* __restrict__ src,
                                           const int* __restrict__ s0a,
                                           const int* __restrict__ s1a,
                                           unsigned short* ah,
                                           const float* __restrict__ lvl4,
                                           const float* __restrict__ gamma,
                                           const float* __restrict__ beta,
                                           int l0patch) {
  unsigned short* cache = (unsigned short*)smemc;  // 220*136*2 = 58.5 KB
  int tid = threadIdx.x;
  int li0 = jb * 32;
  int g0 = 1024 + li0, g1 = g0 + 31;

  int lo[11], wd[11], off[11];
  int acc_off = 0;
  for (int cd = 10; cd >= 1; --cd) {
    int a0 = g0 >> (10 - cd), a1 = g1 >> (10 - cd);
    int l = a0 - SLACK, hgh = a1 + SLACK;
    int lvlo = 1 << cd, lvhi = (2 << cd) - 1;
    l = l < lvlo ? lvlo : l;
    hgh = hgh > lvhi ? lvhi : hgh;
    int w = hgh - l + 1;
    if (acc_off + w > CACHE_ROWS) w = CACHE_ROWS - acc_off;
    if (w < 0) w = 0;
    lo[cd] = l; wd[cd] = w; off[cd] = acc_off; acc_off += w;
  }
  int cdmin = l0patch ? 4 : 1;
  for (int cd = 10; cd >= cdmin; --cd) {
    int w = wd[cd];
    for (int t = tid; t < w * 16; t += NT) {
      int row = t >> 4, seg = t & 15;
      int cr = off[cd] + row;
      *(uint4*)&cache[cr * CSTRIDE + ((seg ^ (cr & 15)) * 8)] =
          *(const uint4*)&ah[(size_t)(b * NN + lo[cd] + row) * AHS + 128 + seg * 8];
    }
  }
  if (l0patch && tid < 112) {
    // compute h rows 2..15 locally from lvl4 (mean + enc + LN + GELU).
    int row = 2 + (tid >> 3), sub = tid & 7, dp = sub * 16;
    int dv = 31 - __clz(row);
    int cnt = 1 << (4 - dv);
    int l4r = (row << (4 - dv)) - 16;
    float v[16];
#pragma unroll
    for (int j = 0; j < 16; ++j) v[j] = 0.f;
    for (int c = 0; c < cnt; ++c) {
      const float* p = &lvl4[(size_t)(b * 16 + l4r + c) * DD + dp];
#pragma unroll
      for (int j = 0; j < 16; ++j) v[j] += p[j];
    }
    float sc = 1.0f / (float)cnt;
    float s1 = 0.f, s2 = 0.f;
#pragma unroll
    for (int j = 0; j < 16; ++j) {
      v[j] = v[j] * sc + enc_val(row, dp + j);
      s1 += v[j]; s2 += v[j] * v[j];
    }
    s1 += __shfl_xor(s1, 1); s2 += __shfl_xor(s2, 1);
    s1 += __shfl_xor(s1, 2); s2 += __shfl_xor(s2, 2);
    s1 += __shfl_xor(s1, 4); s2 += __shfl_xor(s2, 4);
    float mu = s1 * (1.0f / 128.0f);
    float var = s2 * (1.0f / 128.0f) - mu * mu;
    float rinv = rsqrtf(var + 1e-5f);
    __attribute__((aligned(16))) unsigned short o[16];
#pragma unroll
    for (int j = 0; j < 16; ++j)
      o[j] = f2bf(gelu((v[j] - mu) * rinv * gamma[dp + j] + beta[dp + j]));
    int cr = off[dv] + (row - lo[dv]);
    int c0 = sub * 2;
    *(uint4*)&cache[cr * CSTRIDE + ((c0 ^ (cr & 15)) * 8)] = *(uint4*)&o[0];
    *(uint4*)&cache[cr * CSTRIDE + (((c0 + 1) ^ (cr & 15)) * 8)] = *(uint4*)&o[8];
  }
  __syncthreads();

  int leaf = li0 + (tid >> 4);
  int c = tid & 15;
  int r = b * NN + 1024 + leaf;
  int e0 = s0a[r], e1 = s1a[r];
  float acc[8];
#pragma unroll
  for (int j = 0; j < 8; ++j) acc[j] = 0.f;
  for (int e = e0; e < e1; ++e) {
    int g = src[e] - b * NN;
    int lv = 31 - __clz(g);
    int idx = g - lo[lv];
    uint4 u;
    if ((unsigned)idx < (unsigned)wd[lv]) {
      int cr = off[lv] + idx;
      u = *(const uint4*)&cache[cr * CSTRIDE + ((c ^ (cr & 15)) * 8)];
    } else {
      u = *(const uint4*)&ah[(size_t)(b * NN + g) * AHS + 128 + c * 8];
    }
    float f[8];
    cvt8(u, f);
#pragma unroll
    for (int j = 0; j < 8; ++j) acc[j] += f[j];
  }
  float inv = 1.0f / (float)max(e1 - e0, 1);
  __attribute__((aligned(16))) unsigned short o[8];
#pragma unroll
  for (int j = 0; j < 8; ++j) o[j] = f2bf(acc[j] * inv);
  *(uint4*)&ah[(size_t)r * AHS + c * 8] = *(uint4*)&o[0];
}

// ---------------------------------------------------------------------------
// Finish agg for nodes 0..15 of batch b (threads 0..127 only).
__device__ __forceinline__ void ph_topfin(int b,
                                          const float* __restrict__ sroot,
                                          const int* __restrict__ s0a,
                                          const int* __restrict__ s1a,
                                          unsigned short* ah) {
  int d = threadIdx.x;
  float S16[16], h16[16], Sv[16];
#pragma unroll
  for (int j = 0; j < 16; ++j) S16[j] = sroot[(size_t)(b * 16 + j) * DD + d];
#pragma unroll
  for (int j = 0; j < 16; ++j)
    h16[j] = bf2f(ah[(size_t)(b * NN + 16 + j) * AHS + 128 + d]);
#pragma unroll
  for (int k = 8; k < 16; ++k)
    Sv[k] = h16[2 * k - 16] + h16[2 * k - 15] + S16[2 * k - 16] + S16[2 * k - 15];
#pragma unroll
  for (int k = 7; k >= 1; --k)
    Sv[k] = bf2f(ah[(size_t)(b * NN + 2 * k) * AHS + 128 + d]) +
            bf2f(ah[(size_t)(b * NN + 2 * k + 1) * AHS + 128 + d]) +
            Sv[2 * k] + Sv[2 * k + 1];
#pragma unroll
  for (int k = 1; k < 16; ++k) {
    int r = b * NN + k;
    float inv = 1.0f / (float)max(s1a[r] - s0a[r], 1);
    ah[(size_t)r * AHS + d] = f2bf(Sv[k] * inv);
  }
  ah[(size_t)(b * NN) * AHS + d] = f2bf(0.0f);
}

// ---------------------------------------------------------------------------
// x += [agg|h] @ [Wn;Wr] + bias (bf16 MFMA). 64 rows/block: 8 waves =
// 4 m-tiles x 2 n-halves. Optional fused next-layer LN+GELU (cross-wave
// row stats via LDS).
__device__ __forceinline__ void ph_gemm64(char* smemc, int b, int gb,
                                          unsigned short* ah,
                                          const unsigned short* __restrict__ wfl,
                                          const float* __restrict__ bn,
                                          float* __restrict__ x,
                                          const float* __restrict__ gamma,
                                          const float* __restrict__ beta,
                                          const float* __restrict__ sroot,
                                          const int* __restrict__ s0a,
                                          const int* __restrict__ s1a,
                                          int write_h) {
  if (gb == 0) {
    if (threadIdx.x < 128) ph_topfin(b, sroot, s0a, s1a, ah);
    __syncthreads();
  }
  int wave = threadIdx.x >> 6, lane = threadIdx.x & 63;
  int mt = wave >> 1, nh = wave & 1;
  int r0 = b * NN + gb * 64 + mt * 16;
  int m = lane & 15, q = lane >> 4;
  const bf16x8* A0 = (const bf16x8*)(ah + (size_t)(r0 + m) * AHS + q * 8);
  const bf16x8* B  = (const bf16x8*)wfl + lane;
  floatx4 acc[4];
#pragma unroll
  for (int ci = 0; ci < 4; ++ci) acc[ci] = (floatx4){0.f, 0.f, 0.f, 0.f};

#pragma unroll
  for (int kc = 0; kc < 8; ++kc) {
    bf16x8 a0 = A0[kc * 4];
#pragma unroll
    for (int ci = 0; ci < 4; ++ci) {
      bf16x8 bb = B[(kc * 8 + nh * 4 + ci) * 64];
      acc[ci] = __builtin_amdgcn_mfma_f32_16x16x32_bf16(a0, bb, acc[ci], 0, 0, 0);
    }
  }
  float s1[4] = {0.f, 0.f, 0.f, 0.f}, s2[4] = {0.f, 0.f, 0.f, 0.f};
#pragma unroll
  for (int ci = 0; ci < 4; ++ci) {
    int col = (nh * 4 + ci) * 16 + m;
    float bias = bn[col];
#pragma unroll
    for (int r = 0; r < 4; ++r) {
      int row = r0 + q * 4 + r;
      float v = x[(size_t)row * DD + col] + acc[ci][r] + bias;
      x[(size_t)row * DD + col] = v;
      acc[ci][r] = v;
      s1[r] += v; s2[r] += v * v;
    }
  }
  if (write_h) {
#pragma unroll
    for (int r = 0; r < 4; ++r) {
      s1[r] += __shfl_xor(s1[r], 1); s2[r] += __shfl_xor(s2[r], 1);
      s1[r] += __shfl_xor(s1[r], 2); s2[r] += __shfl_xor(s2[r], 2);
      s1[r] += __shfl_xor(s1[r], 4); s2[r] += __shfl_xor(s2[r], 4);
      s1[r] += __shfl_xor(s1[r], 8); s2[r] += __shfl_xor(s2[r], 8);
    }
    float* red = (float*)smemc;   // 256 floats
    int ridx = (mt * 4 + q) * 4;
    if (m == 0) {
#pragma unroll
      for (int r = 0; r < 4; ++r) {
        red[(ridx + r) * 2 + nh] = s1[r];
        red[128 + (ridx + r) * 2 + nh] = s2[r];
      }
    }
    __syncthreads();
    float mu[4], rv[4];
#pragma unroll
    for (int r = 0; r < 4; ++r) {
      float t1 = red[(ridx + r) * 2] + red[(ridx + r) * 2 + 1];
      float t2 = red[128 + (ridx + r) * 2] + red[128 + (ridx + r) * 2 + 1];
      mu[r] = t1 * (1.0f / 128.0f);
      float var = t2 * (1.0f / 128.0f) - mu[r] * mu[r];
      rv[r] = rsqrtf(var + 1e-5f);
    }
#pragma unroll
    for (int ci = 0; ci < 4; ++ci) {
      int col = (nh * 4 + ci) * 16 + m;
      float gm = gamma[col], bt = beta[col];
#pragma unroll
      for (int r = 0; r < 4; ++r) {
        int row = r0 + q * 4 + r;
        float hh = gelu((acc[ci][r] - mu[r]) * rv[r] * gm + bt);
        ah[(size_t)row * AHS + 128 + col] = f2bf(hh);
      }
    }
  }
}

// ---------------------------------------------------------------------------
// Megakernel: 8 independent 32-block groups (one batch each); 4 intra-group
// barriers. All blocks of a group guaranteed resident (1 block/CU at NB=256).
__global__ __launch_bounds__(NT, 1) void k_mega(
    const float* __restrict__ elements, const float* __restrict__ ln_gamma,
    const float* __restrict__ ln_beta, const float* __restrict__ w_nei,
    const float* __restrict__ b_nei, const float* __restrict__ w_root,
    const int* __restrict__ srcv, const int* __restrict__ dstv, int E,
    float* __restrict__ x, int* s0a, int* s1a, float* lvl4, float* sroot,
    unsigned short* wf, unsigned short* ah, int* bar) {
  __shared__ __align__(16) char smem[65536];
  int bid = blockIdx.x, tid = threadIdx.x;
  int b = bid >> 5, gb = bid & 31;
  int Eb = E >> 3;                 // edges per batch (batch-major layout)
  unsigned short* wfg = wf + (size_t)b * 65536;

  // ---- P0: tree+LN0 (gb 0-15) || CSR slice (16-23) || repack (24-31) ----
  if (gb < 16) {
    ph_tree(smem, b, gb, elements, x, lvl4, ah, ln_gamma, ln_beta);
  } else if (gb < 24) {
    int base = b * Eb;
    if (gb == 16 && tid == 0) { s0a[b * NN] = 0; s1a[b * NN] = 0; }
    for (int i = base + (gb - 16) * NT + tid; i < base + Eb; i += 8 * NT) {
      int dv = dstv[i];
      if (i == 0 || dstv[i - 1] != dv) s0a[dv] = i;
      if (i == base + Eb - 1 || dstv[i + 1] != dv) s1a[dv] = i + 1;
    }
  } else {
    int gi = (gb - 24) * NT + tid;   // 0..4095 fragment units
    int lane = gi & 63, ct = (gi >> 6) & 7, kc = gi >> 9;
    int n = ct * 16 + (lane & 15);
    int k = kc * 32 + (lane >> 4) * 8;
    int kk = k & 127;
#pragma unroll
    for (int l = 0; l < 2; ++l) {
      const float* w = (k < 128) ? (w_nei + (size_t)l * DD * DD)
                                 : (w_root + (size_t)l * DD * DD);
      unsigned short* o = wfg + (size_t)l * 32768 + (size_t)gi * 8;
#pragma unroll
      for (int j = 0; j < 8; ++j) o[j] = f2bf(w[(size_t)(kk + j) * DD + n]);
    }
  }
  gbar(bar, 0);

  // ---- P1: top (gb 0) || aggsub L0 (gb 16-31); then leafagg L0 (all) ----
  if (gb == 0)
    ph_top(smem, b, lvl4, x, ah, ln_gamma, ln_beta);
  else if (gb >= 16)
    ph_aggsub(smem, b, gb - 16, ah, s0a, s1a, sroot);
  __syncthreads();
  ph_leafagg(smem, b, gb, srcv, s0a, s1a, ah, lvl4, ln_gamma, ln_beta, 1);
  gbar(bar, 1);

  // ---- P2: gemm L0 (+topfin L0 in gb 0) + fused LN(L1) -> h' ----
  ph_gemm64(smem, b, gb, ah, wfg, b_nei, x, ln_gamma + DD, ln_beta + DD,
            sroot, s0a, s1a, 1);
  gbar(bar, 2);

  // ---- P3: aggsub L1 (gb 0-15); leafagg L1 (all) ----
  if (gb < 16)
    ph_aggsub(smem, b, gb, ah, s0a, s1a, sroot);
  __syncthreads();
  ph_leafagg(smem, b, gb, srcv, s0a, s1a, ah, lvl4, ln_gamma, ln_beta, 0);
  gbar(bar, 3);

  // ---- P4: gemm L1 (+topfin L1) ----
  ph_gemm64(smem, b, gb, ah, wfg + 32768, b_nei + DD, x, ln_gamma, ln_beta,
            sroot, s0a, s1a, 0);
}

// ---------------------------------------------------------------------------
extern "C" void kernel_launch(void* const* d_in, const int* in_sizes, int n_in,
                              void* d_out, int out_size, void* d_ws, size_t ws_size,
                              hipStream_t stream) {
  const float* elements = (const float*)d_in[0];
  const float* ln_gamma = (const float*)d_in[1];
  const float* ln_beta  = (const float*)d_in[2];
  const float* w_nei    = (const float*)d_in[3];
  const float* b_nei    = (const float*)d_in[4];
  const float* w_root   = (const float*)d_in[5];
  const int*   edge     = (const int*)d_in[6];
  int E = in_sizes[6] / 2;
  const int* srcv = edge;
  const int* dstv = edge + E;
  float* x = (float*)d_out;

  char* ws = (char*)d_ws;
  int*            bar   = (int*)ws;                         // 8 KB used
  int*            s0    = (int*)(ws + 65536);               // 64 KB
  int*            s1    = (int*)(ws + 131072);              // 64 KB
  float*          lvl4  = (float*)(ws + 196608);            // 64 KB
  float*          sroot = (float*)(ws + 262144);            // 64 KB
  unsigned short* wf    = (unsigned short*)(ws + 327680);   // 1 MB (8 copies)
  unsigned short* ah    = (unsigned short*)(ws + 327680 + 1048576);  // 8 MB

  hipMemsetAsync(bar, 0, 8192, stream);
  k_mega<<<dim3(NB), dim3(NT), 0, stream>>>(
      elements, ln_gamma, ln_beta, w_nei, b_nei, w_root,
      srcv, dstv, E, x, s0, s1, lvl4, sroot, wf, ah, bar);
}

// Round 9
// 220.044 us; speedup vs baseline: 1.6029x; 1.0368x over previous
//
#include <hip/hip_runtime.h>
#include <hip/hip_bf16.h>

// Problem constants (fixed by the reference file)
#define LEAFN 1024
#define NN    2048            // nodes per batch incl. global node 0
#define BATCH 8
#define DD    128
#define ROWS  (BATCH*NN)      // 16384
#define AHS   256             // ah row stride: [agg(128) | h(128)] bf16
#define NB    256             // megakernel grid size (1 block/CU guaranteed)
#define NT    1024            // threads per block (16 waves/CU)

// ln(10000)/32
#define LOG1E4_OVER_32 0.28782313662425575f

typedef __bf16 bf16x8 __attribute__((ext_vector_type(8)));
typedef float  floatx4 __attribute__((ext_vector_type(4)));
typedef float  floatx2 __attribute__((ext_vector_type(2)));

__device__ __forceinline__ float bf2f(unsigned short u) {
  return __uint_as_float(((unsigned)u) << 16);
}
__device__ __forceinline__ unsigned short f2bf(float f) {
  unsigned u = __float_as_uint(f);
  u += 0x7FFFu + ((u >> 16) & 1u);          // round-to-nearest-even
  return (unsigned short)(u >> 16);
}
__device__ __forceinline__ float gelu(float v) {
  return 0.5f * v * (1.0f + erff(v * 0.70710678118f));
}
__device__ __forceinline__ floatx2 bfpair(unsigned u) {
  floatx2 r;
  r[0] = __uint_as_float(u << 16);
  r[1] = __uint_as_float(u & 0xffff0000u);
  return r;
}

__device__ __forceinline__ float enc_val(int node, int d) {
  float hp, vp;
  if (node == 0) { hp = -0.5f; vp = -1.0f; }
  else {
    int v = 31 - __clz(node);
    hp = (float)(node - (1 << v));
    vp = (float)v;
  }
  float pos = (d < 64) ? hp : vp;
  int i = ((d < 64) ? d : (d - 64)) >> 1;
  float inv = expf(-(float)i * LOG1E4_OVER_32);
  float ang = pos * inv;
  return (d & 1) ? cosf(ang) : sinf(ang);
}

// ---------------------------------------------------------------------------
// Per-GROUP barrier: 32 blocks of group g = bid>>5 (one batch).
__device__ __forceinline__ void gbar(int* bar, int idx) {
  __syncthreads();
  if (threadIdx.x == 0) {
    int g = blockIdx.x >> 5;
    int* base = bar + (idx * 8 + g) * 64;
    __threadfence();                           // release
    if (__hip_atomic_fetch_add(base, 1, __ATOMIC_RELAXED,
                               __HIP_MEMORY_SCOPE_AGENT) == 31)
      __hip_atomic_store(base + 32, 1, __ATOMIC_RELAXED,
                         __HIP_MEMORY_SCOPE_AGENT);
    while (!__hip_atomic_load(base + 32, __ATOMIC_RELAXED,
                              __HIP_MEMORY_SCOPE_AGENT))
      __builtin_amdgcn_s_sleep(2);
    __threadfence();                           // acquire
  }
  __syncthreads();
}

// ---------------------------------------------------------------------------
// Tree build + layer-0 LN/GELU + in-LDS subtree sums (agg depth 4..9).
// (b, s), 1024 thr. Writes: x(d>=4), h->ah, agg->ah, lvl4, sroot.
__device__ __forceinline__ void ph_tree(char* smemc, int b, int s,
                                        const float* __restrict__ elements,
                                        float* __restrict__ x,
                                        float* __restrict__ lvl4,
                                        unsigned short* __restrict__ ah,
                                        const float* __restrict__ gamma,
                                        const float* __restrict__ beta,
                                        float* __restrict__ sroot) {
  float* sm = (float*)smemc;                  // 127*128 floats = 63.5 KB
  int tid = threadIdx.x;
  const float4* src = (const float4*)(elements + (size_t)(b * LEAFN + s * 64) * DD);
  for (int i = tid; i < 2048; i += NT) {
    int f = i * 4;
    int j = f >> 7, d = f & 127;
    *(float4*)&sm[(63 + j) * DD + d] = src[i];
  }
  __syncthreads();
  // mean pyramid (tree compression)
  for (int lv = 5; lv >= 0; --lv) {
    int nodes = 1 << lv;
    for (int idx = tid; idx < nodes * DD; idx += NT) {
      int k = nodes + (idx >> 7);
      int d = idx & 127;
      sm[(k - 1) * DD + d] = 0.5f * (sm[(2 * k - 1) * DD + d] + sm[(2 * k) * DD + d]);
    }
    __syncthreads();
  }
  if (tid < DD) lvl4[(b * 16 + s) * DD + tid] = sm[tid];
  __syncthreads();
  // x = feat + enc; keep x in sm
  for (int idx = tid; idx < 127 * DD; idx += NT) {
    int k = (idx >> 7) + 1;
    int d = idx & 127;
    int lv = 31 - __clz(k);
    int g = ((16 + s) << lv) | (k - (1 << lv));
    float xv = sm[idx] + enc_val(g, d);
    x[((size_t)(b * NN + g)) * DD + d] = xv;
    sm[idx] = xv;
  }
  __syncthreads();
  // LN + GELU: 8 threads/row x 128 rows; h -> ah AND h overwrites sm (fp32)
  {
    int rr = tid >> 3, sub = tid & 7, dp = sub * 16;
    if (rr < 127) {
      float v[16], s1 = 0.f, s2 = 0.f;
#pragma unroll
      for (int j = 0; j < 16; ++j) { v[j] = sm[rr * DD + dp + j]; s1 += v[j]; s2 += v[j] * v[j]; }
      s1 += __shfl_xor(s1, 1); s2 += __shfl_xor(s2, 1);
      s1 += __shfl_xor(s1, 2); s2 += __shfl_xor(s2, 2);
      s1 += __shfl_xor(s1, 4); s2 += __shfl_xor(s2, 4);
      float mu = s1 * (1.0f / 128.0f);
      float var = s2 * (1.0f / 128.0f) - mu * mu;
      float rinv = rsqrtf(var + 1e-5f);
      int k = rr + 1, lv = 31 - __clz(k);
      int g = ((16 + s) << lv) | (k - (1 << lv));
      __attribute__((aligned(16))) unsigned short o[16];
#pragma unroll
      for (int j = 0; j < 16; ++j) {
        float hv = gelu((v[j] - mu) * rinv * gamma[dp + j] + beta[dp + j]);
        o[j] = f2bf(hv);
        sm[rr * DD + dp + j] = hv;             // keep h in LDS for subtree sums
      }
      unsigned short* dst = &ah[(size_t)(b * NN + g) * AHS + 128 + dp];
      *(uint4*)&dst[0] = *(uint4*)&o[0];
      *(uint4*)&dst[8] = *(uint4*)&o[8];
    }
  }
  __syncthreads();
  // subtree-sum pyramid in LDS: S(k) stored at row (2k-1); agg written with
  // closed-form deg = 2^(7-lv) - 2 at local parent level lv (global depth 4+lv).
  for (int lv = 5; lv >= 0; --lv) {
    int nk = 1 << lv;
    float inv = 1.0f / (float)((1 << (7 - lv)) - 2);
    for (int idx = tid; idx < nk * DD; idx += NT) {
      int k = nk + (idx >> 7);
      int d = idx & 127;
      float S = sm[(2 * k - 1) * DD + d] + sm[(2 * k) * DD + d];
      if (lv < 5) S += sm[(4 * k - 1) * DD + d] + sm[(4 * k + 1) * DD + d];
      sm[(2 * k - 1) * DD + d] = S;
      int g = ((16 + s) << lv) | (k - nk);
      ah[(size_t)(b * NN + g) * AHS + d] = f2bf(S * inv);
    }
    __syncthreads();
  }
  // sroot = S(1), stored at row 1
  if (tid < DD) sroot[(size_t)(b * 16 + s) * DD + tid] = sm[DD + tid];
}

// ---------------------------------------------------------------------------
// Top nodes 0..15 of batch b: finish tree, write x and layer-0 h (tid<128).
__device__ __forceinline__ void ph_top(char* smemc, int b,
                                       const float* __restrict__ lvl4,
                                       float* __restrict__ x,
                                       unsigned short* __restrict__ ah,
                                       const float* __restrict__ gamma,
                                       const float* __restrict__ beta) {
  float (*xs)[DD] = (float(*)[DD])smemc;      // 8 KB
  int tid = threadIdx.x;
  if (tid < 128) {
    int d = tid;
    float v[16];
    for (int j = 0; j < 16; ++j) v[j] = lvl4[(b * 16 + j) * DD + d];
    for (int j = 0; j < 8; ++j) v[j] = 0.5f * (v[2 * j] + v[2 * j + 1]);
    for (int j = 0; j < 8; ++j) xs[8 + j][d] = v[j] + enc_val(8 + j, d);
    for (int j = 0; j < 4; ++j) v[j] = 0.5f * (v[2 * j] + v[2 * j + 1]);
    for (int j = 0; j < 4; ++j) xs[4 + j][d] = v[j] + enc_val(4 + j, d);
    for (int j = 0; j < 2; ++j) v[j] = 0.5f * (v[2 * j] + v[2 * j + 1]);
    for (int j = 0; j < 2; ++j) xs[2 + j][d] = v[j] + enc_val(2 + j, d);
    v[0] = 0.5f * (v[0] + v[1]);
    xs[1][d] = v[0] + enc_val(1, d);
    xs[0][d] = -1.0f + enc_val(0, d);
    for (int j = 0; j < 16; ++j) x[((size_t)(b * NN + j)) * DD + d] = xs[j][d];
  }
  __syncthreads();
  if (tid < 128) {
    int rr = tid >> 3, sub = tid & 7, dp = sub * 16;
    float w[16], s1 = 0.f, s2 = 0.f;
#pragma unroll
    for (int j = 0; j < 16; ++j) { w[j] = xs[rr][dp + j]; s1 += w[j]; s2 += w[j] * w[j]; }
    s1 += __shfl_xor(s1, 1); s2 += __shfl_xor(s2, 1);
    s1 += __shfl_xor(s1, 2); s2 += __shfl_xor(s2, 2);
    s1 += __shfl_xor(s1, 4); s2 += __shfl_xor(s2, 4);
    float mu = s1 * (1.0f / 128.0f);
    float var = s2 * (1.0f / 128.0f) - mu * mu;
    float rinv = rsqrtf(var + 1e-5f);
    __attribute__((aligned(16))) unsigned short o[16];
#pragma unroll
    for (int j = 0; j < 16; ++j)
      o[j] = f2bf(gelu((w[j] - mu) * rinv * gamma[dp + j] + beta[dp + j]));
    unsigned short* dst = &ah[(size_t)(b * NN + rr) * AHS + 128 + dp];
    *(uint4*)&dst[0] = *(uint4*)&o[0];
    *(uint4*)&dst[8] = *(uint4*)&o[8];
  }
  __syncthreads();
}

// ---------------------------------------------------------------------------
// Subtree sums for L1 (reads h' from ah). (b, s in 0..15), 1024 thr.
__device__ __forceinline__ void ph_aggsub(char* smemc, int b, int s,
                                          unsigned short* ah,
                                          float* __restrict__ sroot) {
  floatx4 (*S)[32] = (floatx4(*)[32])smemc;   // 32 KB
  int tid = threadIdx.x;

  for (int idx = tid; idx < 32 * 32; idx += NT) {
    int k = 32 + (idx >> 5), q = idx & 31;
    int c = (16 + s) * 64 + (2 * k - 64);
    size_t a0 = (size_t)(b * NN + c) * AHS + 128 + q * 4;
    ushort4 u0 = *(const ushort4*)&ah[a0];
    ushort4 u1 = *(const ushort4*)&ah[a0 + AHS];
    floatx4 v;
    v[0] = bf2f(u0.x) + bf2f(u1.x);
    v[1] = bf2f(u0.y) + bf2f(u1.y);
    v[2] = bf2f(u0.z) + bf2f(u1.z);
    v[3] = bf2f(u0.w) + bf2f(u1.w);
    S[k][q] = v;
    int g = (16 + s) * 32 + (k - 32);
    int r = b * NN + g;
    float inv = 0.5f;                          // deg(depth 9) = 2
    ushort4 o;
    o.x = f2bf(v[0] * inv); o.y = f2bf(v[1] * inv);
    o.z = f2bf(v[2] * inv); o.w = f2bf(v[3] * inv);
    *(ushort4*)&ah[(size_t)r * AHS + q * 4] = o;
  }
  __syncthreads();
  for (int lv = 4; lv >= 0; --lv) {
    int nk = 1 << lv;
    float inv = 1.0f / (float)((1 << (7 - lv)) - 2);
    for (int idx = tid; idx < nk * 32; idx += NT) {
      int k = nk + (idx >> 5), q = idx & 31;
      int c = ((16 + s) << (lv + 1)) | (2 * k - 2 * nk);
      size_t a0 = (size_t)(b * NN + c) * AHS + 128 + q * 4;
      ushort4 u0 = *(const ushort4*)&ah[a0];
      ushort4 u1 = *(const ushort4*)&ah[a0 + AHS];
      floatx4 sc0 = S[2 * k][q], sc1 = S[2 * k + 1][q];
      floatx4 v;
      v[0] = bf2f(u0.x) + bf2f(u1.x) + sc0[0] + sc1[0];
      v[1] = bf2f(u0.y) + bf2f(u1.y) + sc0[1] + sc1[1];
      v[2] = bf2f(u0.z) + bf2f(u1.z) + sc0[2] + sc1[2];
      v[3] = bf2f(u0.w) + bf2f(u1.w) + sc0[3] + sc1[3];
      S[k][q] = v;
      int g = ((16 + s) << lv) | (k - nk);
      int r = b * NN + g;
      ushort4 o;
      o.x = f2bf(v[0] * inv); o.y = f2bf(v[1] * inv);
      o.z = f2bf(v[2] * inv); o.w = f2bf(v[3] * inv);
      *(ushort4*)&ah[(size_t)r * AHS + q * 4] = o;
    }
    __syncthreads();
  }
  for (int q = tid; q < 32; q += NT)
    ((floatx4*)sroot)[(size_t)(b * 16 + s) * 32 + q] = S[1][q];
}

// ---------------------------------------------------------------------------
// Leaf-row gather with per-level LDS window cache + LDS level table.
// (b, jb in [0,32)), 1024 thr = 32 leaves x 2 halves x 16 uint4-chunks.
#define SLACK 10
#define CACHE_ROWS 220
#define CSTRIDE 136
__device__ __forceinline__ void ph_leafagg(char* smemc, int b, int jb,
                                           const int* __restrict__ src,
                                           const int* __restrict__ s0a,
                                           const int* __restrict__ s1a,
                                           unsigned short* ah,
                                           const float* __restrict__ lvl4,
                                           const float* __restrict__ gamma,
                                           const float* __restrict__ beta,
                                           int l0patch) {
  unsigned short* cache = (unsigned short*)smemc;  // 220*136*2 = 59840 B
  int2* wtab = (int2*)(smemc + 60928);             // 11 entries (88 B)
  int tid = threadIdx.x;
  int li0 = jb * 32;
  int g0 = 1024 + li0, g1 = g0 + 31;

  int lo[11], wd[11], off[11];
  int acc_off = 0;
  for (int cd = 10; cd >= 1; --cd) {
    int a0 = g0 >> (10 - cd), a1 = g1 >> (10 - cd);
    int l = a0 - SLACK, hgh = a1 + SLACK;
    int lvlo = 1 << cd, lvhi = (2 << cd) - 1;
    l = l < lvlo ? lvlo : l;
    hgh = hgh > lvhi ? lvhi : hgh;
    int w = hgh - l + 1;
    if (w < 0) w = 0;
    lo[cd] = l; wd[cd] = w; off[cd] = acc_off; acc_off += w;
  }
  if (tid >= 1 && tid <= 10) {
    int cd = tid;
    wtab[cd] = make_int2(off[cd] - lo[cd], lo[cd] | (wd[cd] << 16));
  }
  int cdmin = l0patch ? 4 : 1;
  for (int cd = 10; cd >= cdmin; --cd) {
    int w = wd[cd];
    for (int t = tid; t < w * 16; t += NT) {
      int row = t >> 4, seg = t & 15;
      *(uint4*)&cache[(off[cd] + row) * CSTRIDE + seg * 8] =
          *(const uint4*)&ah[(size_t)(b * NN + lo[cd] + row) * AHS + 128 + seg * 8];
    }
  }
  if (l0patch && tid < 112) {
    // compute h rows 2..15 locally from lvl4 (mean + enc + LN + GELU).
    int row = 2 + (tid >> 3), sub = tid & 7, dp = sub * 16;
    int dv = 31 - __clz(row);
    int cnt = 1 << (4 - dv);
    int l4r = (row << (4 - dv)) - 16;
    float v[16];
#pragma unroll
    for (int j = 0; j < 16; ++j) v[j] = 0.f;
    for (int c = 0; c < cnt; ++c) {
      const float* p = &lvl4[(size_t)(b * 16 + l4r + c) * DD + dp];
#pragma unroll
      for (int j = 0; j < 16; ++j) v[j] += p[j];
    }
    float sc = 1.0f / (float)cnt;
    float s1 = 0.f, s2 = 0.f;
#pragma unroll
    for (int j = 0; j < 16; ++j) {
      v[j] = v[j] * sc + enc_val(row, dp + j);
      s1 += v[j]; s2 += v[j] * v[j];
    }
    s1 += __shfl_xor(s1, 1); s2 += __shfl_xor(s2, 1);
    s1 += __shfl_xor(s1, 2); s2 += __shfl_xor(s2, 2);
    s1 += __shfl_xor(s1, 4); s2 += __shfl_xor(s2, 4);
    float mu = s1 * (1.0f / 128.0f);
    float var = s2 * (1.0f / 128.0f) - mu * mu;
    float rinv = rsqrtf(var + 1e-5f);
    __attribute__((aligned(16))) unsigned short o[16];
#pragma unroll
    for (int j = 0; j < 16; ++j)
      o[j] = f2bf(gelu((v[j] - mu) * rinv * gamma[dp + j] + beta[dp + j]));
    int cr = off[dv] + (row - lo[dv]);
    *(uint4*)&cache[cr * CSTRIDE + sub * 16] = *(uint4*)&o[0];
    *(uint4*)&cache[cr * CSTRIDE + sub * 16 + 8] = *(uint4*)&o[8];
  }
  __syncthreads();

  int leaf = tid >> 5, half = (tid >> 4) & 1, c = tid & 15;
  int r = b * NN + 1024 + li0 + leaf;
  int e0 = s0a[r], e1 = s1a[r];
  floatx2 a0 = {0.f, 0.f}, a1 = {0.f, 0.f}, a2 = {0.f, 0.f}, a3 = {0.f, 0.f};
  for (int e = e0 + half; e < e1; e += 2) {
    int g = src[e] - b * NN;
    int lv = 31 - __clz(g);
    int2 t = wtab[lv];
    int idx = g - (t.y & 0xffff);
    uint4 u;
    if ((unsigned)idx < (unsigned)(t.y >> 16))
      u = *(const uint4*)&cache[(t.x + g) * CSTRIDE + c * 8];
    else
      u = *(const uint4*)&ah[(size_t)(b * NN + g) * AHS + 128 + c * 8];
    a0 += bfpair(u.x); a1 += bfpair(u.y); a2 += bfpair(u.z); a3 += bfpair(u.w);
  }
  __syncthreads();
  float* part = (float*)smemc;                // 32*16*8 floats = 16 KB
  int pidx = ((leaf << 4) | c) * 8;
  if (half) {
    *(floatx2*)&part[pidx + 0] = a0;
    *(floatx2*)&part[pidx + 2] = a1;
    *(floatx2*)&part[pidx + 4] = a2;
    *(floatx2*)&part[pidx + 6] = a3;
  }
  __syncthreads();
  if (!half) {
    float inv = 1.0f / (float)max(e1 - e0, 1);
    float f[8];
    f[0] = (a0[0] + part[pidx + 0]) * inv;
    f[1] = (a0[1] + part[pidx + 1]) * inv;
    f[2] = (a1[0] + part[pidx + 2]) * inv;
    f[3] = (a1[1] + part[pidx + 3]) * inv;
    f[4] = (a2[0] + part[pidx + 4]) * inv;
    f[5] = (a2[1] + part[pidx + 5]) * inv;
    f[6] = (a3[0] + part[pidx + 6]) * inv;
    f[7] = (a3[1] + part[pidx + 7]) * inv;
    __attribute__((aligned(16))) unsigned short o[8];
#pragma unroll
    for (int j = 0; j < 8; ++j) o[j] = f2bf(f[j]);
    *(uint4*)&ah[(size_t)r * AHS + c * 8] = *(uint4*)&o[0];
  }
}

// ---------------------------------------------------------------------------
// Finish agg for nodes 0..15 of batch b (tid<128). Closed-form internal deg.
__device__ __forceinline__ void ph_topfin(int b,
                                          const float* __restrict__ sroot,
                                          unsigned short* ah) {
  int d = threadIdx.x;
  float S16[16], h16[16], Sv[16];
#pragma unroll
  for (int j = 0; j < 16; ++j) S16[j] = sroot[(size_t)(b * 16 + j) * DD + d];
#pragma unroll
  for (int j = 0; j < 16; ++j)
    h16[j] = bf2f(ah[(size_t)(b * NN + 16 + j) * AHS + 128 + d]);
#pragma unroll
  for (int k = 8; k < 16; ++k)
    Sv[k] = h16[2 * k - 16] + h16[2 * k - 15] + S16[2 * k - 16] + S16[2 * k - 15];
#pragma unroll
  for (int k = 7; k >= 1; --k)
    Sv[k] = bf2f(ah[(size_t)(b * NN + 2 * k) * AHS + 128 + d]) +
            bf2f(ah[(size_t)(b * NN + 2 * k + 1) * AHS + 128 + d]) +
            Sv[2 * k] + Sv[2 * k + 1];
#pragma unroll
  for (int k = 1; k < 16; ++k) {
    int dv = 31 - __clz(k);
    float inv = 1.0f / (float)((1 << (11 - dv)) - 2);
    ah[(size_t)(b * NN + k) * AHS + d] = f2bf(Sv[k] * inv);
  }
  ah[(size_t)(b * NN) * AHS + d] = f2bf(0.0f);
}

// ---------------------------------------------------------------------------
// x += [agg|h] @ [Wn;Wr] + bias (bf16 MFMA). 64 rows/block, 16 waves =
// 4 m-tiles x 4 n-quarters. Optional fused next-layer LN+GELU.
__device__ __forceinline__ void ph_gemm64(char* smemc, int b, int gb,
                                          unsigned short* ah,
                                          const unsigned short* __restrict__ wfl,
                                          const float* __restrict__ bn,
                                          float* __restrict__ x,
                                          const float* __restrict__ gamma,
                                          const float* __restrict__ beta,
                                          int write_h) {
  int wave = threadIdx.x >> 6, lane = threadIdx.x & 63;
  int mt = wave >> 2, nq = wave & 3;
  int r0 = b * NN + gb * 64 + mt * 16;
  int m = lane & 15, q = lane >> 4;
  const bf16x8* A0 = (const bf16x8*)(ah + (size_t)(r0 + m) * AHS + q * 8);
  const bf16x8* B  = (const bf16x8*)wfl + lane;
  floatx4 acc[2];
  acc[0] = (floatx4){0.f, 0.f, 0.f, 0.f};
  acc[1] = (floatx4){0.f, 0.f, 0.f, 0.f};
#pragma unroll
  for (int kc = 0; kc < 8; ++kc) {
    bf16x8 a0 = A0[kc * 4];
#pragma unroll
    for (int ci = 0; ci < 2; ++ci) {
      bf16x8 bb = B[(kc * 8 + nq * 2 + ci) * 64];
      acc[ci] = __builtin_amdgcn_mfma_f32_16x16x32_bf16(a0, bb, acc[ci], 0, 0, 0);
    }
  }
  float s1[4] = {0.f, 0.f, 0.f, 0.f}, s2[4] = {0.f, 0.f, 0.f, 0.f};
#pragma unroll
  for (int ci = 0; ci < 2; ++ci) {
    int col = (nq * 2 + ci) * 16 + m;
    float bias = bn[col];
#pragma unroll
    for (int r = 0; r < 4; ++r) {
      int row = r0 + q * 4 + r;
      float v = x[(size_t)row * DD + col] + acc[ci][r] + bias;
      x[(size_t)row * DD + col] = v;
      acc[ci][r] = v;
      s1[r] += v; s2[r] += v * v;
    }
  }
  if (write_h) {
#pragma unroll
    for (int r = 0; r < 4; ++r) {
      s1[r] += __shfl_xor(s1[r], 1); s2[r] += __shfl_xor(s2[r], 1);
      s1[r] += __shfl_xor(s1[r], 2); s2[r] += __shfl_xor(s2[r], 2);
      s1[r] += __shfl_xor(s1[r], 4); s2[r] += __shfl_xor(s2[r], 4);
      s1[r] += __shfl_xor(s1[r], 8); s2[r] += __shfl_xor(s2[r], 8);
    }
    float* red = (float*)smemc;     // 512 floats
    int rb = mt * 16 + q * 4;
    if (m == 0) {
#pragma unroll
      for (int r = 0; r < 4; ++r) {
        red[(rb + r) * 4 + nq] = s1[r];
        red[256 + (rb + r) * 4 + nq] = s2[r];
      }
    }
    __syncthreads();
    float mu[4], rv[4];
#pragma unroll
    for (int r = 0; r < 4; ++r) {
      float t1 = red[(rb + r) * 4] + red[(rb + r) * 4 + 1] +
                 red[(rb + r) * 4 + 2] + red[(rb + r) * 4 + 3];
      float t2 = red[256 + (rb + r) * 4] + red[256 + (rb + r) * 4 + 1] +
                 red[256 + (rb + r) * 4 + 2] + red[256 + (rb + r) * 4 + 3];
      mu[r] = t1 * (1.0f / 128.0f);
      float var = t2 * (1.0f / 128.0f) - mu[r] * mu[r];
      rv[r] = rsqrtf(var + 1e-5f);
    }
#pragma unroll
    for (int ci = 0; ci < 2; ++ci) {
      int col = (nq * 2 + ci) * 16 + m;
      float gm = gamma[col], bt = beta[col];
#pragma unroll
      for (int r = 0; r < 4; ++r) {
        int row = r0 + q * 4 + r;
        float hh = gelu((acc[ci][r] - mu[r]) * rv[r] * gm + bt);
        ah[(size_t)row * AHS + 128 + col] = f2bf(hh);
      }
    }
  }
}

// ---------------------------------------------------------------------------
// Megakernel: 8 groups x 32 blocks (one batch each); 4 intra-group barriers.
__global__ __launch_bounds__(NT, 1) void k_mega(
    const float* __restrict__ elements, const float* __restrict__ ln_gamma,
    const float* __restrict__ ln_beta, const float* __restrict__ w_nei,
    const float* __restrict__ b_nei, const float* __restrict__ w_root,
    const int* __restrict__ srcv, const int* __restrict__ dstv, int E,
    float* __restrict__ x, int* s0a, int* s1a, float* lvl4, float* sroot,
    unsigned short* wf, unsigned short* ah, int* bar) {
  __shared__ __align__(16) char smem[65536];
  int bid = blockIdx.x, tid = threadIdx.x;
  int b = bid >> 5, gb = bid & 31;
  int Eb = E >> 3;                 // edges per batch (batch-major layout)
  unsigned short* wfg = wf + (size_t)b * 65536;

  // ---- P0: tree+LN0+aggL0 (gb 0-15) || CSR (16-23) || repack (24-31) ----
  if (gb < 16) {
    ph_tree(smem, b, gb, elements, x, lvl4, ah, ln_gamma, ln_beta, sroot);
  } else if (gb < 24) {
    int base = b * Eb;
    for (int i = base + (gb - 16) * NT + tid; i < base + Eb; i += 8 * NT) {
      int dv = dstv[i];
      if (i == 0 || dstv[i - 1] != dv) s0a[dv] = i;
      if (i == base + Eb - 1 || dstv[i + 1] != dv) s1a[dv] = i + 1;
    }
  } else {
    int gi = (gb - 24) * NT + tid;   // 8192 = 2 layers x 4096 frag units
    int l = gi >> 12, idx = gi & 4095;
    int lane = idx & 63, ct = (idx >> 6) & 7, kc = idx >> 9;
    int n = ct * 16 + (lane & 15);
    int k = kc * 32 + (lane >> 4) * 8;
    int kk = k & 127;
    const float* w = (k < 128) ? (w_nei + (size_t)l * DD * DD)
                               : (w_root + (size_t)l * DD * DD);
    unsigned short* o = wfg + (size_t)l * 32768 + (size_t)idx * 8;
#pragma unroll
    for (int j = 0; j < 8; ++j) o[j] = f2bf(w[(size_t)(kk + j) * DD + n]);
  }
  gbar(bar, 0);

  // ---- P1: gb0 prelude (top + topfin L0), then leafagg L0 (all) ----
  if (gb == 0) {
    ph_top(smem, b, lvl4, x, ah, ln_gamma, ln_beta);
    if (tid < 128) ph_topfin(b, sroot, ah);
    __syncthreads();
  }
  ph_leafagg(smem, b, gb, srcv, s0a, s1a, ah, lvl4, ln_gamma, ln_beta, 1);
  gbar(bar, 1);

  // ---- P2: gemm L0 + fused LN(L1) -> h' ----
  ph_gemm64(smem, b, gb, ah, wfg, b_nei, x, ln_gamma + DD, ln_beta + DD, 1);
  gbar(bar, 2);

  // ---- P3: aggsub L1 (gb 0-15); leafagg L1 (all) ----
  if (gb < 16) {
    ph_aggsub(smem, b, gb, ah, sroot);
    __syncthreads();
  }
  ph_leafagg(smem, b, gb, srcv, s0a, s1a, ah, lvl4, ln_gamma, ln_beta, 0);
  gbar(bar, 3);

  // ---- P4: topfin L1 (gb0) + gemm L1 ----
  if (gb == 0) {
    if (tid < 128) ph_topfin(b, sroot, ah);
    __syncthreads();
  }
  ph_gemm64(smem, b, gb, ah, wfg + 32768, b_nei + DD, x, ln_gamma, ln_beta, 0);
}

// ---------------------------------------------------------------------------
extern "C" void kernel_launch(void* const* d_in, const int* in_sizes, int n_in,
                              void* d_out, int out_size, void* d_ws, size_t ws_size,
                              hipStream_t stream) {
  const float* elements = (const float*)d_in[0];
  const float* ln_gamma = (const float*)d_in[1];
  const float* ln_beta  = (const float*)d_in[2];
  const float* w_nei    = (const float*)d_in[3];
  const float* b_nei    = (const float*)d_in[4];
  const float* w_root   = (const float*)d_in[5];
  const int*   edge     = (const int*)d_in[6];
  int E = in_sizes[6] / 2;
  const int* srcv = edge;
  const int* dstv = edge + E;
  float* x = (float*)d_out;

  char* ws = (char*)d_ws;
  int*            bar   = (int*)ws;                         // 8 KB used
  int*            s0    = (int*)(ws + 65536);               // 64 KB
  int*            s1    = (int*)(ws + 131072);              // 64 KB
  float*          lvl4  = (float*)(ws + 196608);            // 64 KB
  float*          sroot = (float*)(ws + 262144);            // 64 KB
  unsigned short* wf    = (unsigned short*)(ws + 327680);   // 1 MB (8 copies)
  unsigned short* ah    = (unsigned short*)(ws + 327680 + 1048576);  // 8 MB

  hipMemsetAsync(bar, 0, 8192, stream);
  k_mega<<<dim3(NB), dim3(NT), 0, stream>>>(
      elements, ln_gamma, ln_beta, w_nei, b_nei, w_root,
      srcv, dstv, E, x, s0, s1, lvl4, sroot, wf, ah, bar);
}